// Round 2
// baseline (457.193 us; speedup 1.0000x reference)
//
#include <hip/hip_runtime.h>
#include <math.h>
#include <cstdint>
#include <cstddef>

// ---------------------------------------------------------------------------
// Transformer-XL relative multihead attention, MI355X (gfx950)
// S=1024, M=1024, T=2048, B=4, D=1024, H=16, DH=64
// R10: revert R9 dual-pass (occupancy was not the bottleneck: +4pts occ, -23us
//      regression). k_attn is intra-wave latency-bound -> cross-tile software
//      pipeline: COMPUTE(tile kt)=AC+E+shift (MFMA/LDS) overlapped with
//      FINISH(tile kt-1)=softmax+PV (VALU/exp2) from saved score regs.
//      ldsV double-buffered (PV lags one tile); scores folded to s=AC+Eshift
//      (16 f32 x 2 ping-pong sets); ntile always even -> clean 2x unroll.
//      s_setprio(1) around MFMA clusters. Everything else as R8.
// ---------------------------------------------------------------------------

typedef _Float16 half_t;
typedef _Float16 half8 __attribute__((ext_vector_type(8)));
typedef _Float16 half4v __attribute__((ext_vector_type(4)));
typedef float f32x4 __attribute__((ext_vector_type(4)));

#define S_LEN 1024
#define M_LEN 1024
#define T_LEN 2048
#define BATCH 4
#define NHEAD 16

__device__ inline void async_copy16(const half_t* g, half_t* l) {
  __builtin_amdgcn_global_load_lds(
      (const __attribute__((address_space(1))) void*)g,
      (__attribute__((address_space(3))) void*)l, 16, 0, 0);
}

// ---------------- fused fp32 -> fp16 convert: mem | x | pos ----------------
__global__ __launch_bounds__(256) void k_convert3(const float* __restrict__ mem,
                                                  const float* __restrict__ x,
                                                  const float* __restrict__ pos,
                                                  half_t* __restrict__ cbf,
                                                  half_t* __restrict__ posb) {
  const int i = blockIdx.x * 256 + threadIdx.x;  // grid covers 2621440 float4s
  const float* src;
  half_t* dst;
  int off;
  if (i < 1048576)      { src = mem; dst = cbf;           off = i; }
  else if (i < 2097152) { src = x;   dst = cbf + 4194304; off = i - 1048576; }
  else                  { src = pos; dst = posb;          off = i - 2097152; }
  const float4 v = ((const float4*)src)[off];
  half4v h;
  h[0] = (half_t)v.x; h[1] = (half_t)v.y; h[2] = (half_t)v.z; h[3] = (half_t)v.w;
  ((half4v*)dst)[off] = h;
}

// ------- fused transpose+convert of the 3 weights: [1024][C] -> [C][1024] ----
__global__ __launch_bounds__(256) void k_transpose_w3(const float* __restrict__ Wqkv,
                                                      const float* __restrict__ Wrel,
                                                      const float* __restrict__ Wo,
                                                      half_t* __restrict__ wqkvT,
                                                      half_t* __restrict__ wrelT,
                                                      half_t* __restrict__ woT) {
  __shared__ float tile[64][65];
  const int y = blockIdx.y;
  const float* src; half_t* dst; int C, c0;
  if (y < 48)      { src = Wqkv; dst = wqkvT; C = 3072; c0 = y * 64; }
  else if (y < 64) { src = Wrel; dst = wrelT; C = 1024; c0 = (y - 48) * 64; }
  else             { src = Wo;   dst = woT;   C = 1024; c0 = (y - 64) * 64; }
  const int t = threadIdx.x;
  const int r0 = blockIdx.x * 64;
  const int tx = t & 63, ty4 = t >> 6;
#pragma unroll
  for (int k = 0; k < 16; ++k) {
    int row = k * 4 + ty4;
    tile[row][tx] = src[(size_t)(r0 + row) * C + c0 + tx];
  }
  __syncthreads();
#pragma unroll
  for (int k = 0; k < 16; ++k) {
    int orow = k * 4 + ty4;
    dst[(size_t)(c0 + orow) * 1024 + r0 + tx] = (half_t)tile[tx][orow];
  }
}

// ---------------- fp16 GEMM core (m97 structure + XOR-swizzled LDS) --------
// ld = row stride of A and B (K-dim may be a sub-range for split-K).
__device__ inline void gemm_body(const half_t* __restrict__ A,
                                 const half_t* __restrict__ B,
                                 half_t* __restrict__ C,
                                 int N, int K, int ld, int m0, int n0,
                                 half_t (*ldsA)[64], half_t (*ldsB)[64]) {
  const int t = threadIdx.x;
  const int wave = t >> 6, lane = t & 63, quad = lane >> 4, l15 = lane & 15;
  const int wm = (wave >> 1) * 64, wn = (wave & 1) * 64;
  const int srow = lane >> 3;
  const int scol = ((lane & 7) ^ srow) * 8;  // XOR'd global source chunk
  f32x4 acc[4][4] = {};
  for (int k0 = 0; k0 < K; k0 += 64) {
    __syncthreads();
#pragma unroll
    for (int i = 0; i < 4; ++i) {
      const int r0 = (wave * 4 + i) * 8;
      async_copy16(&A[(size_t)(m0 + r0 + srow) * ld + k0 + scol], &ldsA[r0][0]);
      async_copy16(&B[(size_t)(n0 + r0 + srow) * ld + k0 + scol], &ldsB[r0][0]);
    }
    __syncthreads();
#pragma unroll
    for (int ks = 0; ks < 2; ++ks) {
      half8 af[4], bf[4];
#pragma unroll
      for (int mt = 0; mt < 4; ++mt)
        af[mt] = *(const half8*)&ldsA[wm + mt * 16 + l15][((ks * 4 + quad) ^ (l15 & 7)) * 8];
#pragma unroll
      for (int nt = 0; nt < 4; ++nt)
        bf[nt] = *(const half8*)&ldsB[wn + nt * 16 + l15][((ks * 4 + quad) ^ (l15 & 7)) * 8];
#pragma unroll
      for (int mt = 0; mt < 4; ++mt)
#pragma unroll
        for (int nt = 0; nt < 4; ++nt)
          acc[mt][nt] = __builtin_amdgcn_mfma_f32_16x16x32_f16(af[mt], bf[nt], acc[mt][nt], 0, 0, 0);
    }
  }
#pragma unroll
  for (int mt = 0; mt < 4; ++mt)
#pragma unroll
    for (int nt = 0; nt < 4; ++nt)
#pragma unroll
      for (int r = 0; r < 4; ++r) {
        const int row = m0 + wm + mt * 16 + quad * 4 + r;
        const int col = n0 + wn + nt * 16 + l15;
        C[(size_t)row * N + col] = (half_t)acc[mt][nt][r];
      }
}

// fused qkv (1536 blocks) + pos (128 blocks) GEMM, K=1024 both
__global__ __launch_bounds__(256) void k_gemm_qkv_pos(const half_t* __restrict__ cbf,
                                                      const half_t* __restrict__ wqkvT,
                                                      half_t* __restrict__ qkv,
                                                      const half_t* __restrict__ posb,
                                                      const half_t* __restrict__ wrelT,
                                                      half_t* __restrict__ rb) {
  __shared__ half_t ldsA[128][64];
  __shared__ half_t ldsB[128][64];
  const int bid = blockIdx.x;
  if (bid < 1536)
    gemm_body(cbf, wqkvT, qkv, 3072, 1024, 1024, (bid & 63) * 128, (bid >> 6) * 128, ldsA, ldsB);
  else {
    const int b2 = bid - 1536;
    gemm_body(posb, wrelT, rb, 1024, 1024, 1024, (b2 & 15) * 128, (b2 >> 4) * 128, ldsA, ldsB);
  }
}

// proj GEMM, split-K=2: halves write fp16 partials summed in k_ln.
__global__ __launch_bounds__(256) void k_gemm_proj(const half_t* __restrict__ av,
                                                   const half_t* __restrict__ woT,
                                                   half_t* __restrict__ out0,
                                                   half_t* __restrict__ out1) {
  __shared__ half_t ldsA[128][64];
  __shared__ half_t ldsB[128][64];
  const int bid = blockIdx.x;
  const int h = bid >> 8, b2 = bid & 255;
  gemm_body(av + h * 512, woT + h * 512, h ? out1 : out0,
            1024, 512, 1024, (b2 & 31) * 128, (b2 >> 5) * 128, ldsA, ldsB);
}

// ---------------- V transpose: qkv v-slice -> vT[(b*16+n)*64+dh][T] ----------
__global__ __launch_bounds__(256) void k_transpose_v(const half_t* __restrict__ qkv,
                                                     half_t* __restrict__ vT) {
  __shared__ half_t tile[64][72];
  const int t = threadIdx.x;
  const int t0 = blockIdx.x * 64, bn = blockIdx.y, b = bn >> 4, n = bn & 15;
#pragma unroll
  for (int i = 0; i < 2; ++i) {
    const int ci = t + i * 256;
    const int row = ci >> 3, co = (ci & 7) * 8;
    *(half8*)&tile[row][co] =
        *(const half8*)&qkv[((size_t)(t0 + row) * BATCH + b) * 3072 + 2048 + n * 64 + co];
  }
  __syncthreads();
#pragma unroll
  for (int i = 0; i < 2; ++i) {
    const int ci = t + i * 256;
    const int dh = ci >> 3, to = (ci & 7) * 8;
    half8 v;
#pragma unroll
    for (int j = 0; j < 8; ++j) v[j] = tile[to + j][dh];
    *(half8*)&vT[((size_t)bn * 64 + dh) * 2048 + t0 + to] = v;
  }
}

// ---------------- flash attention with Transformer-XL relative shift --------
// 512 threads = 8 waves; block owns 128 queries. Pairing swizzle (x, 7-x).
// Cross-tile software pipeline: COMPUTE(kt) = AC+E MFMA + bpermute shift ->
// folded scores s[4][4]; FINISH(kt-1) = exp2 softmax + P round-trip + PV
// (reads ldsV[par of kt-1], double-buffered). ntile = 2xe+18 always even.
__global__ __launch_bounds__(512, 4) void k_attn(const half_t* __restrict__ qkv,
                                                 const half_t* __restrict__ rbuf,
                                                 const half_t* __restrict__ vT,
                                                 const float* __restrict__ pbu,
                                                 const float* __restrict__ pbv,
                                                 half_t* __restrict__ av) {
  __shared__ __align__(16) half_t ldsK[64][64];        // [key][dh], XOR chunks
  __shared__ __align__(16) half_t ldsV[2][64][64];     // [dh][key], dbuf, XOR
  __shared__ __align__(16) half_t ldsR[256][64];       // r ring, XOR chunks
  __shared__ __align__(16) half_t ldsP[8][16][72];     // per-wave P (wave-internal)
  const int t = threadIdx.x;
  const int wave = t >> 6, lane = t & 63, quad = lane >> 4, l15 = lane & 15;

  // work-pairing swizzle: CU-co-resident blocks get x and 7-x
  const int li = blockIdx.x + 8 * blockIdx.y;
  const int c = li & 255, kr = li >> 8;
  const int xe = kr == 0 ? (c & 7) : 7 - (c & 7);
  const int bn = (c >> 3) + (kr << 5);
  const int i0 = xe * 128;
  const int b = bn >> 4, n = bn & 15;
  const int i_base = i0 + wave * 16;
  const int p0 = 896 - i0;  // global r-row of ring origin at tile 0

  // q fragments with biases folded in
  half8 qu[2], qv[2];
#pragma unroll
  for (int ks = 0; ks < 2; ++ks) {
    const int dh0 = ks * 32 + quad * 8;
    const half8 qf = *(const half8*)&qkv[((size_t)(M_LEN + i_base + l15) * BATCH + b) * 3072 + n * 64 + dh0];
#pragma unroll
    for (int j = 0; j < 8; ++j) {
      const float qj = (float)qf[j];
      qu[ks][j] = (half_t)(qj + pbu[n * 64 + dh0 + j]);
      qv[ks][j] = (half_t)(qj + pbv[n * 64 + dh0 + j]);
    }
  }

  // E-shift lane rotation constants (loop-invariant): score col cj reads
  // window col cj + 15 - irow; rotation is uniform within a quad per r.
  int bperm_idx[4];
  bool lo_sel[4];
#pragma unroll
  for (int r = 0; r < 4; ++r) {
    const int irow = quad * 4 + r;
    bperm_idx[r] = ((lane & 48) | ((l15 + 15 - irow) & 15)) << 2;
    lo_sel[r] = (l15 <= irow);  // true: window col in tile nt; false: nt+1
  }

  f32x4 oacc[4] = {};
  float lpart[4] = {0.f, 0.f, 0.f, 0.f};
  float sA[4][4], sB[4][4];                     // ping-pong folded scores
  const float k1 = 0.125f * 1.44269504088896f;  // scale * log2(e)
  const float kC = -4.0f * 1.44269504088896f;   // -C * log2(e)

  // staging geometry (K/V and steady-state R: 512 thr cover 64 rows x 8 chunks)
  const int srow = t >> 3, sc3 = t & 7;
  const int sxk = (sc3 ^ (srow & 7)) * 8;

  const int ntile = xe * 2 + 18;                // always even

  // ---- prologue: K/V tile 0, R ring rows [p0, p0+255] (4 passes) ----
  half8 kreg = *(const half8*)&qkv[((size_t)srow * BATCH + b) * 3072 + 1024 + n * 64 + sc3 * 8];
  half8 vreg = *(const half8*)&vT[((size_t)bn * 64 + srow) * 2048 + sc3 * 8];
  half8 rreg4[4];
  int rr4[4], rc4[4];
#pragma unroll
  for (int i = 0; i < 4; ++i) {
    const int ci = t + 512 * i;
    rr4[i] = ci >> 3; rc4[i] = ci & 7;
    const int ps = p0 + rr4[i] > 2047 ? 2047 : p0 + rr4[i];
    rreg4[i] = *(const half8*)&rbuf[(size_t)ps * 1024 + n * 64 + rc4[i] * 8];
  }
  half8 rpre;  // steady-state prefetch reg

  // stage tile kt into ldsK / ldsV[par] / ring
  auto STAGE = [&](int kt, int par) {
    __syncthreads();  // prev-iter LDS reads done; drains vmcnt -> regs ready
    *(half8*)&ldsK[srow][sxk] = kreg;
    *(half8*)&ldsV[par][srow][sxk] = vreg;
    if (kt == 0) {
#pragma unroll
      for (int i = 0; i < 4; ++i) {
        const int pg = p0 + rr4[i];
        *(half8*)&ldsR[pg & 255][(rc4[i] ^ (pg & 7)) * 8] = rreg4[i];
      }
    } else {
      const int pw = kt * 64 + p0 + 192 + srow;  // rows loaded during tile kt-1
      *(half8*)&ldsR[pw & 255][(sc3 ^ (pw & 7)) * 8] = rpre;
    }
    __syncthreads();
  };

  // prefetch tile ktn into regs (regs dead after STAGE's writes)
  auto PREFETCH = [&](int ktn) {
    if (ktn < ntile) {
      const int j0n = ktn * 64;
      kreg = *(const half8*)&qkv[((size_t)(j0n + srow) * BATCH + b) * 3072 + 1024 + n * 64 + sc3 * 8];
      vreg = *(const half8*)&vT[((size_t)bn * 64 + srow) * 2048 + j0n + sc3 * 8];
      const int pn = j0n + p0 + 192 + srow;  // new ring rows for tile ktn
      const int pc = pn > 2047 ? 2047 : pn;
      rpre = *(const half8*)&rbuf[(size_t)pc * 1024 + n * 64 + sc3 * 8];
    }
  };

  // AC + E MFMA for tile kt, bpermute E-shift, fold into S = AC + Eshift
  auto COMPUTE = [&](int kt, float (&S)[4][4]) {
    const int j0 = kt * 64;
    __builtin_amdgcn_s_setprio(1);
    // AC = (q+u) @ K^T
    f32x4 ac[4] = {};
#pragma unroll
    for (int ks = 0; ks < 2; ++ks)
#pragma unroll
      for (int nt = 0; nt < 4; ++nt) {
        const int row = nt * 16 + l15;
        const half8 kf = *(const half8*)&ldsK[row][((ks * 4 + quad) ^ (row & 7)) * 8];
        ac[nt] = __builtin_amdgcn_mfma_f32_16x16x32_f16(qu[ks], kf, ac[nt], 0, 0, 0);
      }
    // E window: E[m][c] = (q+v) . r[window c], width 80 (ring reads)
    const int rbg = j0 + p0 + 112 - wave * 16;  // wave's window start (global)
    f32x4 ea[5] = {};
#pragma unroll
    for (int ks = 0; ks < 2; ++ks)
#pragma unroll
      for (int et = 0; et < 5; ++et) {
        const int pr = rbg + et * 16 + l15;
        const half8 rf = *(const half8*)&ldsR[pr & 255][((ks * 4 + quad) ^ (pr & 7)) * 8];
        ea[et] = __builtin_amdgcn_mfma_f32_16x16x32_f16(qv[ks], rf, ea[et], 0, 0, 0);
      }
    __builtin_amdgcn_s_setprio(0);
    // E shift via in-register bpermute (f32), fold AC + Eshift -> S
#pragma unroll
    for (int r = 0; r < 4; ++r) {
      float rot[5];
#pragma unroll
      for (int et = 0; et < 5; ++et)
        rot[et] = __int_as_float(
            __builtin_amdgcn_ds_bpermute(bperm_idx[r], __float_as_int(ea[et][r])));
#pragma unroll
      for (int nt = 0; nt < 4; ++nt)
        S[r][nt] = ac[nt][r] + (lo_sel[r] ? rot[nt] : rot[nt + 1]);
    }
  };

  // softmax + P round-trip + PV for tile ktp (scores in S, V in ldsV[par])
  auto FINISH = [&](int ktp, float (&S)[4][4], int par) {
    const int j0p = ktp * 64;
    const bool maskt = j0p > i_base + 960;
#pragma unroll
    for (int r = 0; r < 4; ++r) {
      const int irow = quad * 4 + r;
      const int ig = i_base + irow;
      float psum = 0.f;
#pragma unroll
      for (int nt = 0; nt < 4; ++nt) {
        const int cj = nt * 16 + l15;
        float p = __builtin_amdgcn_exp2f(fmaf(S[r][nt], k1, kC));
        if (maskt && (j0p + cj > ig + M_LEN)) p = 0.f;
        psum += p;
        ldsP[wave][irow][cj] = (half_t)p;
      }
      lpart[r] += psum;
    }
    __builtin_amdgcn_wave_barrier();  // P round trip is wave-internal
    half8 pa[2];
#pragma unroll
    for (int ks = 0; ks < 2; ++ks)
      pa[ks] = *(const half8*)&ldsP[wave][l15][ks * 32 + quad * 8];
    __builtin_amdgcn_s_setprio(1);
#pragma unroll
    for (int ks = 0; ks < 2; ++ks)
#pragma unroll
      for (int dnt = 0; dnt < 4; ++dnt) {
        const int row = dnt * 16 + l15;
        const half8 vf = *(const half8*)&ldsV[par][row][((ks * 4 + quad) ^ (row & 7)) * 8];
        oacc[dnt] = __builtin_amdgcn_mfma_f32_16x16x32_f16(pa[ks], vf, oacc[dnt], 0, 0, 0);
      }
    __builtin_amdgcn_s_setprio(0);
  };

  // ---- main pipelined loop (2x unrolled; ntile even) ----
  for (int kt = 0; kt < ntile; kt += 2) {
    STAGE(kt, 0);
    PREFETCH(kt + 1);
    COMPUTE(kt, sA);
    if (kt > 0) FINISH(kt - 1, sB, 1);   // overlap: softmax/PV of prev tile
    STAGE(kt + 1, 1);
    PREFETCH(kt + 2);
    COMPUTE(kt + 1, sB);
    FINISH(kt, sA, 0);
  }
  FINISH(ntile - 1, sB, 1);              // drain the pipeline

  // final l-sum reduction + normalize + store
#pragma unroll
  for (int r = 0; r < 4; ++r) {
    float l = lpart[r];
#pragma unroll
    for (int off = 1; off < 16; off <<= 1) l += __shfl_xor(l, off);
    const float inv = 1.0f / l;
    const int ig = i_base + quad * 4 + r;
#pragma unroll
    for (int dnt = 0; dnt < 4; ++dnt)
      av[((size_t)ig * BATCH + b) * 1024 + n * 64 + dnt * 16 + l15] = (half_t)(oacc[dnt][r] * inv);
  }
}

// -------- residual + LayerNorm (one block per row; sums 2 fp16 partials) ----
__global__ __launch_bounds__(256) void k_ln(const float* __restrict__ x,
                                            const half_t* __restrict__ ao0,
                                            const half_t* __restrict__ ao1,
                                            const float* __restrict__ gamma,
                                            const float* __restrict__ beta,
                                            float* __restrict__ out) {
  const int row = blockIdx.x;
  const int t = threadIdx.x;
  const float4 xv = ((const float4*)(x + (size_t)row * 1024))[t];
  const half4v a4 = ((const half4v*)(ao0 + (size_t)row * 1024))[t];
  const half4v b4 = ((const half4v*)(ao1 + (size_t)row * 1024))[t];
  const float y0 = xv.x + (float)a4[0] + (float)b4[0];
  const float y1 = xv.y + (float)a4[1] + (float)b4[1];
  const float y2 = xv.z + (float)a4[2] + (float)b4[2];
  const float y3 = xv.w + (float)a4[3] + (float)b4[3];
  float s = y0 + y1 + y2 + y3;
  float ss = y0 * y0 + y1 * y1 + y2 * y2 + y3 * y3;
#pragma unroll
  for (int off = 1; off < 64; off <<= 1) {
    s += __shfl_xor(s, off);
    ss += __shfl_xor(ss, off);
  }
  __shared__ float sb[4], ssb[4];
  if ((t & 63) == 0) { sb[t >> 6] = s; ssb[t >> 6] = ss; }
  __syncthreads();
  s = sb[0] + sb[1] + sb[2] + sb[3];
  ss = ssb[0] + ssb[1] + ssb[2] + ssb[3];
  const float mean = s * (1.f / 1024.f);
  const float var = ss * (1.f / 1024.f) - mean * mean;
  const float rstd = rsqrtf(var + 1e-5f);
  const float4 g = ((const float4*)gamma)[t];
  const float4 be = ((const float4*)beta)[t];
  float4 o;
  o.x = (y0 - mean) * rstd * g.x + be.x;
  o.y = (y1 - mean) * rstd * g.y + be.y;
  o.z = (y2 - mean) * rstd * g.z + be.z;
  o.w = (y3 - mean) * rstd * g.w + be.w;
  ((float4*)(out + (size_t)row * 1024))[t] = o;
}

// ---------------------------------------------------------------------------
extern "C" void kernel_launch(void* const* d_in, const int* in_sizes, int n_in,
                              void* d_out, int out_size, void* d_ws, size_t ws_size,
                              hipStream_t stream) {
  const float* x     = (const float*)d_in[0];
  const float* pos   = (const float*)d_in[1];
  const float* pbu   = (const float*)d_in[2];
  const float* pbv   = (const float*)d_in[3];
  const float* mem   = (const float*)d_in[4];
  const float* Wqkv  = (const float*)d_in[5];
  const float* Wrel  = (const float*)d_in[6];
  const float* Wo    = (const float*)d_in[7];
  const float* gamma = (const float*)d_in[8];
  const float* beta  = (const float*)d_in[9];
  float* out = (float*)d_out;

  half_t* ws    = (half_t*)d_ws;
  half_t* cbf   = ws;                 // [8192][1024]
  half_t* posb  = cbf + 8388608;      // [2048][1024]
  half_t* wqkvT = posb + 2097152;     // [3072][1024]
  half_t* wrelT = wqkvT + 3145728;    // [1024][1024]
  half_t* woT   = wrelT + 1048576;    // [1024][1024]
  half_t* qkv   = woT + 1048576;      // [8192][3072]
  half_t* rb    = qkv + 25165824;     // [2048][1024]
  half_t* vT    = rb + 2097152;       // [64][64][2048]
  half_t* av    = vT + 8388608;       // [4096][1024]
  half_t* aout0 = qkv;                // reuse qkv region (partial 0)
  half_t* aout1 = qkv + 4194304;      // partial 1

  k_convert3<<<10240, 256, 0, stream>>>(mem, x, pos, cbf, posb);
  k_transpose_w3<<<dim3(16, 80), 256, 0, stream>>>(Wqkv, Wrel, Wo, wqkvT, wrelT, woT);
  k_gemm_qkv_pos<<<1664, 256, 0, stream>>>(cbf, wqkvT, qkv, posb, wrelT, rb);
  k_transpose_v<<<dim3(32, 64), 256, 0, stream>>>(qkv, vT);
  k_attn<<<dim3(8, 64), 512, 0, stream>>>(qkv, rb, vT, pbu, pbv, av);
  k_gemm_proj<<<512, 256, 0, stream>>>(av, woT, aout0, aout1);
  k_ln<<<4096, 256, 0, stream>>>(x, aout0, aout1, gamma, beta, out);
}

// Round 3
// 419.963 us; speedup vs baseline: 1.0887x; 1.0887x over previous
//
#include <hip/hip_runtime.h>
#include <math.h>
#include <cstdint>
#include <cstddef>

// ---------------------------------------------------------------------------
// Transformer-XL relative multihead attention, MI355X (gfx950)
// S=1024, M=1024, T=2048, B=4, D=1024, H=16, DH=64
// R11: R10's cross-tile pipeline re-done spill-free. R10's lambdas took
//      float(&)[4][4] refs -> address-taken -> scratch (WRITE_SIZE 285MB).
//      Now: macros, named f32x4 arrays, compile-time indices only (R8's
//      proven register-resident pattern). COMPUTE(kt)=AC+E MFMA issue;
//      FINISH(kt-1)=exp2 softmax + PV from saved folded scores (independent
//      of in-flight MFMAs); FOLD(kt) afterwards. ldsV double-buffered,
//      ntile even -> 2x unroll. Everything else exactly R8.
// ---------------------------------------------------------------------------

typedef _Float16 half_t;
typedef _Float16 half8 __attribute__((ext_vector_type(8)));
typedef _Float16 half4v __attribute__((ext_vector_type(4)));
typedef float f32x4 __attribute__((ext_vector_type(4)));

#define S_LEN 1024
#define M_LEN 1024
#define T_LEN 2048
#define BATCH 4
#define NHEAD 16

__device__ inline void async_copy16(const half_t* g, half_t* l) {
  __builtin_amdgcn_global_load_lds(
      (const __attribute__((address_space(1))) void*)g,
      (__attribute__((address_space(3))) void*)l, 16, 0, 0);
}

// ---------------- fused fp32 -> fp16 convert: mem | x | pos ----------------
__global__ __launch_bounds__(256) void k_convert3(const float* __restrict__ mem,
                                                  const float* __restrict__ x,
                                                  const float* __restrict__ pos,
                                                  half_t* __restrict__ cbf,
                                                  half_t* __restrict__ posb) {
  const int i = blockIdx.x * 256 + threadIdx.x;  // grid covers 2621440 float4s
  const float* src;
  half_t* dst;
  int off;
  if (i < 1048576)      { src = mem; dst = cbf;           off = i; }
  else if (i < 2097152) { src = x;   dst = cbf + 4194304; off = i - 1048576; }
  else                  { src = pos; dst = posb;          off = i - 2097152; }
  const float4 v = ((const float4*)src)[off];
  half4v h;
  h[0] = (half_t)v.x; h[1] = (half_t)v.y; h[2] = (half_t)v.z; h[3] = (half_t)v.w;
  ((half4v*)dst)[off] = h;
}

// ------- fused transpose+convert of the 3 weights: [1024][C] -> [C][1024] ----
__global__ __launch_bounds__(256) void k_transpose_w3(const float* __restrict__ Wqkv,
                                                      const float* __restrict__ Wrel,
                                                      const float* __restrict__ Wo,
                                                      half_t* __restrict__ wqkvT,
                                                      half_t* __restrict__ wrelT,
                                                      half_t* __restrict__ woT) {
  __shared__ float tile[64][65];
  const int y = blockIdx.y;
  const float* src; half_t* dst; int C, c0;
  if (y < 48)      { src = Wqkv; dst = wqkvT; C = 3072; c0 = y * 64; }
  else if (y < 64) { src = Wrel; dst = wrelT; C = 1024; c0 = (y - 48) * 64; }
  else             { src = Wo;   dst = woT;   C = 1024; c0 = (y - 64) * 64; }
  const int t = threadIdx.x;
  const int r0 = blockIdx.x * 64;
  const int tx = t & 63, ty4 = t >> 6;
#pragma unroll
  for (int k = 0; k < 16; ++k) {
    int row = k * 4 + ty4;
    tile[row][tx] = src[(size_t)(r0 + row) * C + c0 + tx];
  }
  __syncthreads();
#pragma unroll
  for (int k = 0; k < 16; ++k) {
    int orow = k * 4 + ty4;
    dst[(size_t)(c0 + orow) * 1024 + r0 + tx] = (half_t)tile[tx][orow];
  }
}

// ---------------- fp16 GEMM core (m97 structure + XOR-swizzled LDS) --------
// ld = row stride of A and B (K-dim may be a sub-range for split-K).
__device__ inline void gemm_body(const half_t* __restrict__ A,
                                 const half_t* __restrict__ B,
                                 half_t* __restrict__ C,
                                 int N, int K, int ld, int m0, int n0,
                                 half_t (*ldsA)[64], half_t (*ldsB)[64]) {
  const int t = threadIdx.x;
  const int wave = t >> 6, lane = t & 63, quad = lane >> 4, l15 = lane & 15;
  const int wm = (wave >> 1) * 64, wn = (wave & 1) * 64;
  const int srow = lane >> 3;
  const int scol = ((lane & 7) ^ srow) * 8;  // XOR'd global source chunk
  f32x4 acc[4][4] = {};
  for (int k0 = 0; k0 < K; k0 += 64) {
    __syncthreads();
#pragma unroll
    for (int i = 0; i < 4; ++i) {
      const int r0 = (wave * 4 + i) * 8;
      async_copy16(&A[(size_t)(m0 + r0 + srow) * ld + k0 + scol], &ldsA[r0][0]);
      async_copy16(&B[(size_t)(n0 + r0 + srow) * ld + k0 + scol], &ldsB[r0][0]);
    }
    __syncthreads();
#pragma unroll
    for (int ks = 0; ks < 2; ++ks) {
      half8 af[4], bf[4];
#pragma unroll
      for (int mt = 0; mt < 4; ++mt)
        af[mt] = *(const half8*)&ldsA[wm + mt * 16 + l15][((ks * 4 + quad) ^ (l15 & 7)) * 8];
#pragma unroll
      for (int nt = 0; nt < 4; ++nt)
        bf[nt] = *(const half8*)&ldsB[wn + nt * 16 + l15][((ks * 4 + quad) ^ (l15 & 7)) * 8];
#pragma unroll
      for (int mt = 0; mt < 4; ++mt)
#pragma unroll
        for (int nt = 0; nt < 4; ++nt)
          acc[mt][nt] = __builtin_amdgcn_mfma_f32_16x16x32_f16(af[mt], bf[nt], acc[mt][nt], 0, 0, 0);
    }
  }
#pragma unroll
  for (int mt = 0; mt < 4; ++mt)
#pragma unroll
    for (int nt = 0; nt < 4; ++nt)
#pragma unroll
      for (int r = 0; r < 4; ++r) {
        const int row = m0 + wm + mt * 16 + quad * 4 + r;
        const int col = n0 + wn + nt * 16 + l15;
        C[(size_t)row * N + col] = (half_t)acc[mt][nt][r];
      }
}

// fused qkv (1536 blocks) + pos (128 blocks) GEMM, K=1024 both
__global__ __launch_bounds__(256) void k_gemm_qkv_pos(const half_t* __restrict__ cbf,
                                                      const half_t* __restrict__ wqkvT,
                                                      half_t* __restrict__ qkv,
                                                      const half_t* __restrict__ posb,
                                                      const half_t* __restrict__ wrelT,
                                                      half_t* __restrict__ rb) {
  __shared__ half_t ldsA[128][64];
  __shared__ half_t ldsB[128][64];
  const int bid = blockIdx.x;
  if (bid < 1536)
    gemm_body(cbf, wqkvT, qkv, 3072, 1024, 1024, (bid & 63) * 128, (bid >> 6) * 128, ldsA, ldsB);
  else {
    const int b2 = bid - 1536;
    gemm_body(posb, wrelT, rb, 1024, 1024, 1024, (b2 & 15) * 128, (b2 >> 4) * 128, ldsA, ldsB);
  }
}

// proj GEMM, split-K=2: halves write fp16 partials summed in k_ln.
__global__ __launch_bounds__(256) void k_gemm_proj(const half_t* __restrict__ av,
                                                   const half_t* __restrict__ woT,
                                                   half_t* __restrict__ out0,
                                                   half_t* __restrict__ out1) {
  __shared__ half_t ldsA[128][64];
  __shared__ half_t ldsB[128][64];
  const int bid = blockIdx.x;
  const int h = bid >> 8, b2 = bid & 255;
  gemm_body(av + h * 512, woT + h * 512, h ? out1 : out0,
            1024, 512, 1024, (b2 & 31) * 128, (b2 >> 5) * 128, ldsA, ldsB);
}

// ---------------- V transpose: qkv v-slice -> vT[(b*16+n)*64+dh][T] ----------
__global__ __launch_bounds__(256) void k_transpose_v(const half_t* __restrict__ qkv,
                                                     half_t* __restrict__ vT) {
  __shared__ half_t tile[64][72];
  const int t = threadIdx.x;
  const int t0 = blockIdx.x * 64, bn = blockIdx.y, b = bn >> 4, n = bn & 15;
#pragma unroll
  for (int i = 0; i < 2; ++i) {
    const int ci = t + i * 256;
    const int row = ci >> 3, co = (ci & 7) * 8;
    *(half8*)&tile[row][co] =
        *(const half8*)&qkv[((size_t)(t0 + row) * BATCH + b) * 3072 + 2048 + n * 64 + co];
  }
  __syncthreads();
#pragma unroll
  for (int i = 0; i < 2; ++i) {
    const int ci = t + i * 256;
    const int dh = ci >> 3, to = (ci & 7) * 8;
    half8 v;
#pragma unroll
    for (int j = 0; j < 8; ++j) v[j] = tile[to + j][dh];
    *(half8*)&vT[((size_t)bn * 64 + dh) * 2048 + t0 + to] = v;
  }
}

// ---------------- flash attention with Transformer-XL relative shift --------
// 512 threads = 8 waves; block owns 128 queries. Pairing swizzle (x, 7-x).
// Cross-tile pipeline, all state in named registers (no address-taken arrays):
//   STAGE(kt) -> PREFETCH -> QKMFMA(kt) -> FINISH(kt-1) -> FOLD(kt)
// ldsV double-buffered (PV lags one tile); ntile = 2xe+18 always even.

#define ATT_STAGE(kt_, par_)                                                    \
  do {                                                                          \
    __syncthreads();                                                            \
    *(half8*)&ldsK[srow][sxk] = kreg;                                           \
    *(half8*)&ldsV[par_][srow][sxk] = vreg;                                     \
    if ((kt_) == 0) {                                                           \
      _Pragma("unroll") for (int i_ = 0; i_ < 4; ++i_) {                        \
        const int pg_ = p0 + rr4[i_];                                           \
        *(half8*)&ldsR[pg_ & 255][(rc4[i_] ^ (pg_ & 7)) * 8] = rreg4[i_];       \
      }                                                                         \
    } else {                                                                    \
      const int pw_ = (kt_) * 64 + p0 + 128 + srow;                             \
      *(half8*)&ldsR[pw_ & 255][(sc3 ^ (pw_ & 7)) * 8] = rpre;                  \
    }                                                                           \
    __syncthreads();                                                            \
  } while (0)

#define ATT_PREFETCH(ktn_)                                                      \
  do {                                                                          \
    if ((ktn_) < ntile) {                                                       \
      const int j0n_ = (ktn_) * 64;                                             \
      kreg = *(const half8*)&qkv[((size_t)(j0n_ + srow) * BATCH + b) * 3072 +   \
                                 1024 + n * 64 + sc3 * 8];                      \
      vreg = *(const half8*)&vT[((size_t)bn * 64 + srow) * 2048 + j0n_ +        \
                                sc3 * 8];                                       \
      const int pn_ = (ktn_) * 64 + p0 + 128 + srow;                            \
      const int pc_ = pn_ > 2047 ? 2047 : pn_;                                  \
      rpre = *(const half8*)&rbuf[(size_t)pc_ * 1024 + n * 64 + sc3 * 8];       \
    }                                                                           \
  } while (0)

#define ATT_QKMFMA(kt_, AC_, EA_)                                               \
  do {                                                                          \
    const int j0_ = (kt_) * 64;                                                 \
    _Pragma("unroll") for (int z_ = 0; z_ < 4; ++z_) AC_[z_] = fzero;           \
    _Pragma("unroll") for (int z_ = 0; z_ < 5; ++z_) EA_[z_] = fzero;           \
    __builtin_amdgcn_s_setprio(1);                                              \
    _Pragma("unroll") for (int ks_ = 0; ks_ < 2; ++ks_)                         \
      _Pragma("unroll") for (int nt_ = 0; nt_ < 4; ++nt_) {                     \
        const int row_ = nt_ * 16 + l15;                                        \
        const half8 kf_ =                                                       \
            *(const half8*)&ldsK[row_][((ks_ * 4 + quad) ^ (row_ & 7)) * 8];    \
        AC_[nt_] = __builtin_amdgcn_mfma_f32_16x16x32_f16(qu[ks_], kf_,         \
                                                          AC_[nt_], 0, 0, 0);   \
      }                                                                         \
    const int rbg_ = j0_ + p0 + 112 - wave * 16;                                \
    _Pragma("unroll") for (int ks_ = 0; ks_ < 2; ++ks_)                         \
      _Pragma("unroll") for (int et_ = 0; et_ < 5; ++et_) {                     \
        const int pr_ = rbg_ + et_ * 16 + l15;                                  \
        const half8 rf_ =                                                       \
            *(const half8*)&ldsR[pr_ & 255][((ks_ * 4 + quad) ^ (pr_ & 7)) * 8];\
        EA_[et_] = __builtin_amdgcn_mfma_f32_16x16x32_f16(qv[ks_], rf_,         \
                                                          EA_[et_], 0, 0, 0);   \
      }                                                                         \
    __builtin_amdgcn_s_setprio(0);                                              \
  } while (0)

#define ATT_FOLD(AC_, EA_, S_)                                                  \
  do {                                                                          \
    _Pragma("unroll") for (int r_ = 0; r_ < 4; ++r_) {                          \
      const float rot0_ = __int_as_float(__builtin_amdgcn_ds_bpermute(          \
          bperm_idx[r_], __float_as_int(EA_[0][r_])));                          \
      const float rot1_ = __int_as_float(__builtin_amdgcn_ds_bpermute(          \
          bperm_idx[r_], __float_as_int(EA_[1][r_])));                          \
      const float rot2_ = __int_as_float(__builtin_amdgcn_ds_bpermute(          \
          bperm_idx[r_], __float_as_int(EA_[2][r_])));                          \
      const float rot3_ = __int_as_float(__builtin_amdgcn_ds_bpermute(          \
          bperm_idx[r_], __float_as_int(EA_[3][r_])));                          \
      const float rot4_ = __int_as_float(__builtin_amdgcn_ds_bpermute(          \
          bperm_idx[r_], __float_as_int(EA_[4][r_])));                          \
      S_[0][r_] = AC_[0][r_] + (lo_sel[r_] ? rot0_ : rot1_);                    \
      S_[1][r_] = AC_[1][r_] + (lo_sel[r_] ? rot1_ : rot2_);                    \
      S_[2][r_] = AC_[2][r_] + (lo_sel[r_] ? rot2_ : rot3_);                    \
      S_[3][r_] = AC_[3][r_] + (lo_sel[r_] ? rot3_ : rot4_);                    \
    }                                                                           \
  } while (0)

#define ATT_FINISH(ktp_, S_, par_)                                              \
  do {                                                                          \
    const int j0p_ = (ktp_) * 64;                                               \
    const bool maskt_ = j0p_ > i_base + 960;                                    \
    _Pragma("unroll") for (int r_ = 0; r_ < 4; ++r_) {                          \
      const int irow_ = quad * 4 + r_;                                          \
      const int ig_ = i_base + irow_;                                           \
      float psum_ = 0.f;                                                        \
      _Pragma("unroll") for (int nt_ = 0; nt_ < 4; ++nt_) {                     \
        const int cj_ = nt_ * 16 + l15;                                         \
        float p_ = __builtin_amdgcn_exp2f(fmaf(S_[nt_][r_], k1, kC));           \
        if (maskt_ && (j0p_ + cj_ > ig_ + M_LEN)) p_ = 0.f;                     \
        psum_ += p_;                                                            \
        ldsP[wave][irow_][cj_] = (half_t)p_;                                    \
      }                                                                         \
      lpart[r_] += psum_;                                                       \
    }                                                                           \
    __builtin_amdgcn_wave_barrier();                                            \
    half8 pa0_ = *(const half8*)&ldsP[wave][l15][quad * 8];                     \
    half8 pa1_ = *(const half8*)&ldsP[wave][l15][32 + quad * 8];                \
    __builtin_amdgcn_s_setprio(1);                                              \
    _Pragma("unroll") for (int dnt_ = 0; dnt_ < 4; ++dnt_) {                    \
      const int row_ = dnt_ * 16 + l15;                                         \
      const half8 vf_ =                                                         \
          *(const half8*)&ldsV[par_][row_][((quad) ^ (row_ & 7)) * 8];          \
      oacc[dnt_] = __builtin_amdgcn_mfma_f32_16x16x32_f16(pa0_, vf_,            \
                                                          oacc[dnt_], 0, 0, 0); \
    }                                                                           \
    _Pragma("unroll") for (int dnt_ = 0; dnt_ < 4; ++dnt_) {                    \
      const int row_ = dnt_ * 16 + l15;                                         \
      const half8 vf_ =                                                         \
          *(const half8*)&ldsV[par_][row_][((4 + quad) ^ (row_ & 7)) * 8];      \
      oacc[dnt_] = __builtin_amdgcn_mfma_f32_16x16x32_f16(pa1_, vf_,            \
                                                          oacc[dnt_], 0, 0, 0); \
    }                                                                           \
    __builtin_amdgcn_s_setprio(0);                                              \
  } while (0)

__global__ __launch_bounds__(512, 4) void k_attn(const half_t* __restrict__ qkv,
                                                 const half_t* __restrict__ rbuf,
                                                 const half_t* __restrict__ vT,
                                                 const float* __restrict__ pbu,
                                                 const float* __restrict__ pbv,
                                                 half_t* __restrict__ av) {
  __shared__ __align__(16) half_t ldsK[64][64];        // [key][dh], XOR chunks
  __shared__ __align__(16) half_t ldsV[2][64][64];     // [dh][key], dbuf, XOR
  __shared__ __align__(16) half_t ldsR[256][64];       // r ring, XOR chunks
  __shared__ __align__(16) half_t ldsP[8][16][72];     // per-wave P (wave-internal)
  const int t = threadIdx.x;
  const int wave = t >> 6, lane = t & 63, quad = lane >> 4, l15 = lane & 15;

  // work-pairing swizzle: CU-co-resident blocks get x and 7-x
  const int li = blockIdx.x + 8 * blockIdx.y;
  const int c = li & 255, kr = li >> 8;
  const int xe = kr == 0 ? (c & 7) : 7 - (c & 7);
  const int bn = (c >> 3) + (kr << 5);
  const int i0 = xe * 128;
  const int b = bn >> 4, n = bn & 15;
  const int i_base = i0 + wave * 16;
  const int p0 = 896 - i0;  // global r-row of ring origin at tile 0

  // q fragments with biases folded in
  half8 qu[2], qv[2];
#pragma unroll
  for (int ks = 0; ks < 2; ++ks) {
    const int dh0 = ks * 32 + quad * 8;
    const half8 qf = *(const half8*)&qkv[((size_t)(M_LEN + i_base + l15) * BATCH + b) * 3072 + n * 64 + dh0];
#pragma unroll
    for (int j = 0; j < 8; ++j) {
      const float qj = (float)qf[j];
      qu[ks][j] = (half_t)(qj + pbu[n * 64 + dh0 + j]);
      qv[ks][j] = (half_t)(qj + pbv[n * 64 + dh0 + j]);
    }
  }

  // E-shift lane rotation constants (loop-invariant): score col cj reads
  // window col cj + 15 - irow; rotation is uniform within a quad per r.
  int bperm_idx[4];
  bool lo_sel[4];
#pragma unroll
  for (int r = 0; r < 4; ++r) {
    const int irow = quad * 4 + r;
    bperm_idx[r] = ((lane & 48) | ((l15 + 15 - irow) & 15)) << 2;
    lo_sel[r] = (l15 <= irow);  // true: window col in tile nt; false: nt+1
  }

  const f32x4 fzero = {0.f, 0.f, 0.f, 0.f};
  f32x4 oacc[4] = {};
  float lpart[4] = {0.f, 0.f, 0.f, 0.f};
  f32x4 ac[4], ea[5], sc0[4], sc1[4];           // all compile-time indexed
  const float k1 = 0.125f * 1.44269504088896f;  // scale * log2(e)
  const float kC = -4.0f * 1.44269504088896f;   // -C * log2(e)

  // staging geometry (K/V and steady-state R: 512 thr cover 64 rows x 8 chunks)
  const int srow = t >> 3, sc3 = t & 7;
  const int sxk = (sc3 ^ (srow & 7)) * 8;

  const int ntile = xe * 2 + 18;                // always even

  // ---- prologue: K/V tile 0, R ring rows [p0, p0+255] (4 passes) ----
  half8 kreg = *(const half8*)&qkv[((size_t)srow * BATCH + b) * 3072 + 1024 + n * 64 + sc3 * 8];
  half8 vreg = *(const half8*)&vT[((size_t)bn * 64 + srow) * 2048 + sc3 * 8];
  half8 rreg4[4];
  int rr4[4], rc4[4];
#pragma unroll
  for (int i = 0; i < 4; ++i) {
    const int ci = t + 512 * i;
    rr4[i] = ci >> 3; rc4[i] = ci & 7;
    const int ps = p0 + rr4[i] > 2047 ? 2047 : p0 + rr4[i];
    rreg4[i] = *(const half8*)&rbuf[(size_t)ps * 1024 + n * 64 + rc4[i] * 8];
  }
  half8 rpre;  // steady-state prefetch reg

  // ---- main pipelined loop (2x unrolled; ntile even) ----
  for (int kt = 0; kt < ntile; kt += 2) {
    ATT_STAGE(kt, 0);
    ATT_PREFETCH(kt + 1);
    ATT_QKMFMA(kt, ac, ea);
    if (kt > 0) ATT_FINISH(kt - 1, sc1, 1);   // overlap with in-flight MFMAs
    ATT_FOLD(ac, ea, sc0);
    ATT_STAGE(kt + 1, 1);
    ATT_PREFETCH(kt + 2);
    ATT_QKMFMA(kt + 1, ac, ea);
    ATT_FINISH(kt, sc0, 0);
    ATT_FOLD(ac, ea, sc1);
  }
  ATT_FINISH(ntile - 1, sc1, 1);              // drain the pipeline

  // final l-sum reduction + normalize + store
#pragma unroll
  for (int r = 0; r < 4; ++r) {
    float l = lpart[r];
#pragma unroll
    for (int off = 1; off < 16; off <<= 1) l += __shfl_xor(l, off);
    const float inv = 1.0f / l;
    const int ig = i_base + quad * 4 + r;
#pragma unroll
    for (int dnt = 0; dnt < 4; ++dnt)
      av[((size_t)ig * BATCH + b) * 1024 + n * 64 + dnt * 16 + l15] = (half_t)(oacc[dnt][r] * inv);
  }
}

// -------- residual + LayerNorm (one block per row; sums 2 fp16 partials) ----
__global__ __launch_bounds__(256) void k_ln(const float* __restrict__ x,
                                            const half_t* __restrict__ ao0,
                                            const half_t* __restrict__ ao1,
                                            const float* __restrict__ gamma,
                                            const float* __restrict__ beta,
                                            float* __restrict__ out) {
  const int row = blockIdx.x;
  const int t = threadIdx.x;
  const float4 xv = ((const float4*)(x + (size_t)row * 1024))[t];
  const half4v a4 = ((const half4v*)(ao0 + (size_t)row * 1024))[t];
  const half4v b4 = ((const half4v*)(ao1 + (size_t)row * 1024))[t];
  const float y0 = xv.x + (float)a4[0] + (float)b4[0];
  const float y1 = xv.y + (float)a4[1] + (float)b4[1];
  const float y2 = xv.z + (float)a4[2] + (float)b4[2];
  const float y3 = xv.w + (float)a4[3] + (float)b4[3];
  float s = y0 + y1 + y2 + y3;
  float ss = y0 * y0 + y1 * y1 + y2 * y2 + y3 * y3;
#pragma unroll
  for (int off = 1; off < 64; off <<= 1) {
    s += __shfl_xor(s, off);
    ss += __shfl_xor(ss, off);
  }
  __shared__ float sb[4], ssb[4];
  if ((t & 63) == 0) { sb[t >> 6] = s; ssb[t >> 6] = ss; }
  __syncthreads();
  s = sb[0] + sb[1] + sb[2] + sb[3];
  ss = ssb[0] + ssb[1] + ssb[2] + ssb[3];
  const float mean = s * (1.f / 1024.f);
  const float var = ss * (1.f / 1024.f) - mean * mean;
  const float rstd = rsqrtf(var + 1e-5f);
  const float4 g = ((const float4*)gamma)[t];
  const float4 be = ((const float4*)beta)[t];
  float4 o;
  o.x = (y0 - mean) * rstd * g.x + be.x;
  o.y = (y1 - mean) * rstd * g.y + be.y;
  o.z = (y2 - mean) * rstd * g.z + be.z;
  o.w = (y3 - mean) * rstd * g.w + be.w;
  ((float4*)(out + (size_t)row * 1024))[t] = o;
}

// ---------------------------------------------------------------------------
extern "C" void kernel_launch(void* const* d_in, const int* in_sizes, int n_in,
                              void* d_out, int out_size, void* d_ws, size_t ws_size,
                              hipStream_t stream) {
  const float* x     = (const float*)d_in[0];
  const float* pos   = (const float*)d_in[1];
  const float* pbu   = (const float*)d_in[2];
  const float* pbv   = (const float*)d_in[3];
  const float* mem   = (const float*)d_in[4];
  const float* Wqkv  = (const float*)d_in[5];
  const float* Wrel  = (const float*)d_in[6];
  const float* Wo    = (const float*)d_in[7];
  const float* gamma = (const float*)d_in[8];
  const float* beta  = (const float*)d_in[9];
  float* out = (float*)d_out;

  half_t* ws    = (half_t*)d_ws;
  half_t* cbf   = ws;                 // [8192][1024]
  half_t* posb  = cbf + 8388608;      // [2048][1024]
  half_t* wqkvT = posb + 2097152;     // [3072][1024]
  half_t* wrelT = wqkvT + 3145728;    // [1024][1024]
  half_t* woT   = wrelT + 1048576;    // [1024][1024]
  half_t* qkv   = woT + 1048576;      // [8192][3072]
  half_t* rb    = qkv + 25165824;     // [2048][1024]
  half_t* vT    = rb + 2097152;       // [64][64][2048]
  half_t* av    = vT + 8388608;       // [4096][1024]
  half_t* aout0 = qkv;                // reuse qkv region (partial 0)
  half_t* aout1 = qkv + 4194304;      // partial 1

  k_convert3<<<10240, 256, 0, stream>>>(mem, x, pos, cbf, posb);
  k_transpose_w3<<<dim3(16, 80), 256, 0, stream>>>(Wqkv, Wrel, Wo, wqkvT, wrelT, woT);
  k_gemm_qkv_pos<<<1664, 256, 0, stream>>>(cbf, wqkvT, qkv, posb, wrelT, rb);
  k_transpose_v<<<dim3(32, 64), 256, 0, stream>>>(qkv, vT);
  k_attn<<<dim3(8, 64), 512, 0, stream>>>(qkv, rb, vT, pbu, pbv, av);
  k_gemm_proj<<<512, 256, 0, stream>>>(av, woT, aout0, aout1);
  k_ln<<<4096, 256, 0, stream>>>(x, aout0, aout1, gamma, beta, out);
}

// Round 4
// 372.286 us; speedup vs baseline: 1.2281x; 1.1281x over previous
//
#include <hip/hip_runtime.h>
#include <math.h>
#include <cstdint>
#include <cstddef>

// ---------------------------------------------------------------------------
// Transformer-XL relative multihead attention, MI355X (gfx950)
// S=1024, M=1024, T=2048, B=4, D=1024, H=16, DH=64
// R12: spill-free cross-tile pipeline. R11 spilled (~25 VGPR over the 128 cap:
//      WRITE_SIZE 172MB). Cuts: single score set S (SOFTMAX(kt-1) -> FOLD(kt)
//      -> PV(kt-1) ordering), tile-0 ring fill peeled out of the loop (frees
//      rreg4/rr4/rc4), lo_sel inlined. Peak liveness ~120 <= 128.
//      Overlap mechanism: SOFTMAX's exp2/VALU chain issues while QKMFMA(kt)'s
//      18 MFMAs drain; FOLD's bpermute is the first consumer of ea.
// ---------------------------------------------------------------------------

typedef _Float16 half_t;
typedef _Float16 half8 __attribute__((ext_vector_type(8)));
typedef _Float16 half4v __attribute__((ext_vector_type(4)));
typedef float f32x4 __attribute__((ext_vector_type(4)));

#define S_LEN 1024
#define M_LEN 1024
#define T_LEN 2048
#define BATCH 4
#define NHEAD 16

__device__ inline void async_copy16(const half_t* g, half_t* l) {
  __builtin_amdgcn_global_load_lds(
      (const __attribute__((address_space(1))) void*)g,
      (__attribute__((address_space(3))) void*)l, 16, 0, 0);
}

// ---------------- fused fp32 -> fp16 convert: mem | x | pos ----------------
__global__ __launch_bounds__(256) void k_convert3(const float* __restrict__ mem,
                                                  const float* __restrict__ x,
                                                  const float* __restrict__ pos,
                                                  half_t* __restrict__ cbf,
                                                  half_t* __restrict__ posb) {
  const int i = blockIdx.x * 256 + threadIdx.x;  // grid covers 2621440 float4s
  const float* src;
  half_t* dst;
  int off;
  if (i < 1048576)      { src = mem; dst = cbf;           off = i; }
  else if (i < 2097152) { src = x;   dst = cbf + 4194304; off = i - 1048576; }
  else                  { src = pos; dst = posb;          off = i - 2097152; }
  const float4 v = ((const float4*)src)[off];
  half4v h;
  h[0] = (half_t)v.x; h[1] = (half_t)v.y; h[2] = (half_t)v.z; h[3] = (half_t)v.w;
  ((half4v*)dst)[off] = h;
}

// ------- fused transpose+convert of the 3 weights: [1024][C] -> [C][1024] ----
__global__ __launch_bounds__(256) void k_transpose_w3(const float* __restrict__ Wqkv,
                                                      const float* __restrict__ Wrel,
                                                      const float* __restrict__ Wo,
                                                      half_t* __restrict__ wqkvT,
                                                      half_t* __restrict__ wrelT,
                                                      half_t* __restrict__ woT) {
  __shared__ float tile[64][65];
  const int y = blockIdx.y;
  const float* src; half_t* dst; int C, c0;
  if (y < 48)      { src = Wqkv; dst = wqkvT; C = 3072; c0 = y * 64; }
  else if (y < 64) { src = Wrel; dst = wrelT; C = 1024; c0 = (y - 48) * 64; }
  else             { src = Wo;   dst = woT;   C = 1024; c0 = (y - 64) * 64; }
  const int t = threadIdx.x;
  const int r0 = blockIdx.x * 64;
  const int tx = t & 63, ty4 = t >> 6;
#pragma unroll
  for (int k = 0; k < 16; ++k) {
    int row = k * 4 + ty4;
    tile[row][tx] = src[(size_t)(r0 + row) * C + c0 + tx];
  }
  __syncthreads();
#pragma unroll
  for (int k = 0; k < 16; ++k) {
    int orow = k * 4 + ty4;
    dst[(size_t)(c0 + orow) * 1024 + r0 + tx] = (half_t)tile[tx][orow];
  }
}

// ---------------- fp16 GEMM core (m97 structure + XOR-swizzled LDS) --------
// ld = row stride of A and B (K-dim may be a sub-range for split-K).
__device__ inline void gemm_body(const half_t* __restrict__ A,
                                 const half_t* __restrict__ B,
                                 half_t* __restrict__ C,
                                 int N, int K, int ld, int m0, int n0,
                                 half_t (*ldsA)[64], half_t (*ldsB)[64]) {
  const int t = threadIdx.x;
  const int wave = t >> 6, lane = t & 63, quad = lane >> 4, l15 = lane & 15;
  const int wm = (wave >> 1) * 64, wn = (wave & 1) * 64;
  const int srow = lane >> 3;
  const int scol = ((lane & 7) ^ srow) * 8;  // XOR'd global source chunk
  f32x4 acc[4][4] = {};
  for (int k0 = 0; k0 < K; k0 += 64) {
    __syncthreads();
#pragma unroll
    for (int i = 0; i < 4; ++i) {
      const int r0 = (wave * 4 + i) * 8;
      async_copy16(&A[(size_t)(m0 + r0 + srow) * ld + k0 + scol], &ldsA[r0][0]);
      async_copy16(&B[(size_t)(n0 + r0 + srow) * ld + k0 + scol], &ldsB[r0][0]);
    }
    __syncthreads();
#pragma unroll
    for (int ks = 0; ks < 2; ++ks) {
      half8 af[4], bf[4];
#pragma unroll
      for (int mt = 0; mt < 4; ++mt)
        af[mt] = *(const half8*)&ldsA[wm + mt * 16 + l15][((ks * 4 + quad) ^ (l15 & 7)) * 8];
#pragma unroll
      for (int nt = 0; nt < 4; ++nt)
        bf[nt] = *(const half8*)&ldsB[wn + nt * 16 + l15][((ks * 4 + quad) ^ (l15 & 7)) * 8];
#pragma unroll
      for (int mt = 0; mt < 4; ++mt)
#pragma unroll
        for (int nt = 0; nt < 4; ++nt)
          acc[mt][nt] = __builtin_amdgcn_mfma_f32_16x16x32_f16(af[mt], bf[nt], acc[mt][nt], 0, 0, 0);
    }
  }
#pragma unroll
  for (int mt = 0; mt < 4; ++mt)
#pragma unroll
    for (int nt = 0; nt < 4; ++nt)
#pragma unroll
      for (int r = 0; r < 4; ++r) {
        const int row = m0 + wm + mt * 16 + quad * 4 + r;
        const int col = n0 + wn + nt * 16 + l15;
        C[(size_t)row * N + col] = (half_t)acc[mt][nt][r];
      }
}

// fused qkv (1536 blocks) + pos (128 blocks) GEMM, K=1024 both
__global__ __launch_bounds__(256) void k_gemm_qkv_pos(const half_t* __restrict__ cbf,
                                                      const half_t* __restrict__ wqkvT,
                                                      half_t* __restrict__ qkv,
                                                      const half_t* __restrict__ posb,
                                                      const half_t* __restrict__ wrelT,
                                                      half_t* __restrict__ rb) {
  __shared__ half_t ldsA[128][64];
  __shared__ half_t ldsB[128][64];
  const int bid = blockIdx.x;
  if (bid < 1536)
    gemm_body(cbf, wqkvT, qkv, 3072, 1024, 1024, (bid & 63) * 128, (bid >> 6) * 128, ldsA, ldsB);
  else {
    const int b2 = bid - 1536;
    gemm_body(posb, wrelT, rb, 1024, 1024, 1024, (b2 & 15) * 128, (b2 >> 4) * 128, ldsA, ldsB);
  }
}

// proj GEMM, split-K=2: halves write fp16 partials summed in k_ln.
__global__ __launch_bounds__(256) void k_gemm_proj(const half_t* __restrict__ av,
                                                   const half_t* __restrict__ woT,
                                                   half_t* __restrict__ out0,
                                                   half_t* __restrict__ out1) {
  __shared__ half_t ldsA[128][64];
  __shared__ half_t ldsB[128][64];
  const int bid = blockIdx.x;
  const int h = bid >> 8, b2 = bid & 255;
  gemm_body(av + h * 512, woT + h * 512, h ? out1 : out0,
            1024, 512, 1024, (b2 & 31) * 128, (b2 >> 5) * 128, ldsA, ldsB);
}

// ---------------- V transpose: qkv v-slice -> vT[(b*16+n)*64+dh][T] ----------
__global__ __launch_bounds__(256) void k_transpose_v(const half_t* __restrict__ qkv,
                                                     half_t* __restrict__ vT) {
  __shared__ half_t tile[64][72];
  const int t = threadIdx.x;
  const int t0 = blockIdx.x * 64, bn = blockIdx.y, b = bn >> 4, n = bn & 15;
#pragma unroll
  for (int i = 0; i < 2; ++i) {
    const int ci = t + i * 256;
    const int row = ci >> 3, co = (ci & 7) * 8;
    *(half8*)&tile[row][co] =
        *(const half8*)&qkv[((size_t)(t0 + row) * BATCH + b) * 3072 + 2048 + n * 64 + co];
  }
  __syncthreads();
#pragma unroll
  for (int i = 0; i < 2; ++i) {
    const int ci = t + i * 256;
    const int dh = ci >> 3, to = (ci & 7) * 8;
    half8 v;
#pragma unroll
    for (int j = 0; j < 8; ++j) v[j] = tile[to + j][dh];
    *(half8*)&vT[((size_t)bn * 64 + dh) * 2048 + t0 + to] = v;
  }
}

// ---------------- flash attention with Transformer-XL relative shift --------
// 512 threads = 8 waves; block owns 128 queries. Pairing swizzle (x, 7-x).
// Spill-free cross-tile pipeline (single score set S):
//   peel: stage(0)+prefetch(1) ; QKMFMA(0) ; FOLD->S
//   loop kt=1..ntile-1: STAGE(kt) ; PREFETCH(kt+1) ; QKMFMA(kt) ;
//                       SOFTMAX(kt-1,S) ; FOLD(kt)->S ; PV(kt-1)
//   drain: SOFTMAX(ntile-1,S) ; PV(ntile-1)
// ldsV double-buffered (PV lags one tile); ntile = 2xe+18 always even.

#define ATT_STAGE(kt_, par_)                                                    \
  do {                                                                          \
    __syncthreads();                                                            \
    *(half8*)&ldsK[srow][sxk] = kreg;                                           \
    *(half8*)&ldsV[par_][srow][sxk] = vreg;                                     \
    const int pw_ = (kt_) * 64 + p0 + 128 + srow;                               \
    *(half8*)&ldsR[pw_ & 255][(sc3 ^ (pw_ & 7)) * 8] = rpre;                    \
    __syncthreads();                                                            \
  } while (0)

#define ATT_PREFETCH(ktn_)                                                      \
  do {                                                                          \
    if ((ktn_) < ntile) {                                                       \
      const int j0n_ = (ktn_) * 64;                                             \
      kreg = *(const half8*)&qkv[((size_t)(j0n_ + srow) * BATCH + b) * 3072 +   \
                                 1024 + n * 64 + sc3 * 8];                      \
      vreg = *(const half8*)&vT[((size_t)bn * 64 + srow) * 2048 + j0n_ +        \
                                sc3 * 8];                                       \
      const int pn_ = j0n_ + p0 + 128 + srow;                                   \
      const int pc_ = pn_ > 2047 ? 2047 : pn_;                                  \
      rpre = *(const half8*)&rbuf[(size_t)pc_ * 1024 + n * 64 + sc3 * 8];       \
    }                                                                           \
  } while (0)

#define ATT_QKMFMA(kt_)                                                         \
  do {                                                                          \
    const int j0_ = (kt_) * 64;                                                 \
    _Pragma("unroll") for (int z_ = 0; z_ < 4; ++z_) ac[z_] = fzero;            \
    _Pragma("unroll") for (int z_ = 0; z_ < 5; ++z_) ea[z_] = fzero;            \
    __builtin_amdgcn_s_setprio(1);                                              \
    _Pragma("unroll") for (int ks_ = 0; ks_ < 2; ++ks_)                         \
      _Pragma("unroll") for (int nt_ = 0; nt_ < 4; ++nt_) {                     \
        const int row_ = nt_ * 16 + l15;                                        \
        const half8 kf_ =                                                       \
            *(const half8*)&ldsK[row_][((ks_ * 4 + quad) ^ (row_ & 7)) * 8];    \
        ac[nt_] = __builtin_amdgcn_mfma_f32_16x16x32_f16(qu[ks_], kf_,          \
                                                         ac[nt_], 0, 0, 0);     \
      }                                                                         \
    const int rbg_ = j0_ + p0 + 112 - wave * 16;                                \
    _Pragma("unroll") for (int ks_ = 0; ks_ < 2; ++ks_)                         \
      _Pragma("unroll") for (int et_ = 0; et_ < 5; ++et_) {                     \
        const int pr_ = rbg_ + et_ * 16 + l15;                                  \
        const half8 rf_ =                                                       \
            *(const half8*)&ldsR[pr_ & 255][((ks_ * 4 + quad) ^ (pr_ & 7)) * 8];\
        ea[et_] = __builtin_amdgcn_mfma_f32_16x16x32_f16(qv[ks_], rf_,          \
                                                         ea[et_], 0, 0, 0);     \
      }                                                                         \
    __builtin_amdgcn_s_setprio(0);                                              \
  } while (0)

#define ATT_FOLD()                                                              \
  do {                                                                          \
    _Pragma("unroll") for (int r_ = 0; r_ < 4; ++r_) {                          \
      const bool lo_ = l15 <= quad * 4 + r_;                                    \
      const float rot0_ = __int_as_float(__builtin_amdgcn_ds_bpermute(          \
          bperm_idx[r_], __float_as_int(ea[0][r_])));                           \
      const float rot1_ = __int_as_float(__builtin_amdgcn_ds_bpermute(          \
          bperm_idx[r_], __float_as_int(ea[1][r_])));                           \
      const float rot2_ = __int_as_float(__builtin_amdgcn_ds_bpermute(          \
          bperm_idx[r_], __float_as_int(ea[2][r_])));                           \
      const float rot3_ = __int_as_float(__builtin_amdgcn_ds_bpermute(          \
          bperm_idx[r_], __float_as_int(ea[3][r_])));                           \
      const float rot4_ = __int_as_float(__builtin_amdgcn_ds_bpermute(          \
          bperm_idx[r_], __float_as_int(ea[4][r_])));                           \
      S[0][r_] = ac[0][r_] + (lo_ ? rot0_ : rot1_);                             \
      S[1][r_] = ac[1][r_] + (lo_ ? rot1_ : rot2_);                             \
      S[2][r_] = ac[2][r_] + (lo_ ? rot2_ : rot3_);                             \
      S[3][r_] = ac[3][r_] + (lo_ ? rot3_ : rot4_);                             \
    }                                                                           \
  } while (0)

#define ATT_SOFTMAX(ktp_)                                                       \
  do {                                                                          \
    const int j0p_ = (ktp_) * 64;                                               \
    const bool maskt_ = j0p_ > i_base + 960;                                    \
    _Pragma("unroll") for (int r_ = 0; r_ < 4; ++r_) {                          \
      const int irow_ = quad * 4 + r_;                                          \
      const int ig_ = i_base + irow_;                                           \
      float psum_ = 0.f;                                                        \
      _Pragma("unroll") for (int nt_ = 0; nt_ < 4; ++nt_) {                     \
        const int cj_ = nt_ * 16 + l15;                                         \
        float p_ = __builtin_amdgcn_exp2f(fmaf(S[nt_][r_], k1, kC));            \
        if (maskt_ && (j0p_ + cj_ > ig_ + M_LEN)) p_ = 0.f;                     \
        psum_ += p_;                                                            \
        ldsP[wave][irow_][cj_] = (half_t)p_;                                    \
      }                                                                         \
      lpart[r_] += psum_;                                                       \
    }                                                                           \
    __builtin_amdgcn_wave_barrier();                                            \
  } while (0)

#define ATT_PV(par_)                                                            \
  do {                                                                          \
    half8 pa0_ = *(const half8*)&ldsP[wave][l15][quad * 8];                     \
    half8 pa1_ = *(const half8*)&ldsP[wave][l15][32 + quad * 8];                \
    __builtin_amdgcn_s_setprio(1);                                              \
    _Pragma("unroll") for (int dnt_ = 0; dnt_ < 4; ++dnt_) {                    \
      const int row_ = dnt_ * 16 + l15;                                         \
      const half8 vf_ =                                                         \
          *(const half8*)&ldsV[par_][row_][((quad) ^ (row_ & 7)) * 8];          \
      oacc[dnt_] = __builtin_amdgcn_mfma_f32_16x16x32_f16(pa0_, vf_,            \
                                                          oacc[dnt_], 0, 0, 0); \
    }                                                                           \
    _Pragma("unroll") for (int dnt_ = 0; dnt_ < 4; ++dnt_) {                    \
      const int row_ = dnt_ * 16 + l15;                                         \
      const half8 vf_ =                                                         \
          *(const half8*)&ldsV[par_][row_][((4 + quad) ^ (row_ & 7)) * 8];      \
      oacc[dnt_] = __builtin_amdgcn_mfma_f32_16x16x32_f16(pa1_, vf_,            \
                                                          oacc[dnt_], 0, 0, 0); \
    }                                                                           \
    __builtin_amdgcn_s_setprio(0);                                              \
  } while (0)

__global__ __launch_bounds__(512, 4) void k_attn(const half_t* __restrict__ qkv,
                                                 const half_t* __restrict__ rbuf,
                                                 const half_t* __restrict__ vT,
                                                 const float* __restrict__ pbu,
                                                 const float* __restrict__ pbv,
                                                 half_t* __restrict__ av) {
  __shared__ __align__(16) half_t ldsK[64][64];        // [key][dh], XOR chunks
  __shared__ __align__(16) half_t ldsV[2][64][64];     // [dh][key], dbuf, XOR
  __shared__ __align__(16) half_t ldsR[256][64];       // r ring, XOR chunks
  __shared__ __align__(16) half_t ldsP[8][16][72];     // per-wave P (wave-internal)
  const int t = threadIdx.x;
  const int wave = t >> 6, lane = t & 63, quad = lane >> 4, l15 = lane & 15;

  // work-pairing swizzle: CU-co-resident blocks get x and 7-x
  const int li = blockIdx.x + 8 * blockIdx.y;
  const int c = li & 255, kr = li >> 8;
  const int xe = kr == 0 ? (c & 7) : 7 - (c & 7);
  const int bn = (c >> 3) + (kr << 5);
  const int i0 = xe * 128;
  const int b = bn >> 4, n = bn & 15;
  const int i_base = i0 + wave * 16;
  const int p0 = 896 - i0;  // global r-row of ring origin at tile 0

  // q fragments with biases folded in
  half8 qu[2], qv[2];
#pragma unroll
  for (int ks = 0; ks < 2; ++ks) {
    const int dh0 = ks * 32 + quad * 8;
    const half8 qf = *(const half8*)&qkv[((size_t)(M_LEN + i_base + l15) * BATCH + b) * 3072 + n * 64 + dh0];
#pragma unroll
    for (int j = 0; j < 8; ++j) {
      const float qj = (float)qf[j];
      qu[ks][j] = (half_t)(qj + pbu[n * 64 + dh0 + j]);
      qv[ks][j] = (half_t)(qj + pbv[n * 64 + dh0 + j]);
    }
  }

  // E-shift lane rotation constants (loop-invariant): score col cj reads
  // window col cj + 15 - irow; rotation is uniform within a quad per r.
  int bperm_idx[4];
#pragma unroll
  for (int r = 0; r < 4; ++r) {
    const int irow = quad * 4 + r;
    bperm_idx[r] = ((lane & 48) | ((l15 + 15 - irow) & 15)) << 2;
  }

  const f32x4 fzero = {0.f, 0.f, 0.f, 0.f};
  f32x4 oacc[4] = {};
  float lpart[4] = {0.f, 0.f, 0.f, 0.f};
  f32x4 ac[4], ea[5], S[4];                     // all compile-time indexed
  const float k1 = 0.125f * 1.44269504088896f;  // scale * log2(e)
  const float kC = -4.0f * 1.44269504088896f;   // -C * log2(e)

  // staging geometry (K/V and steady-state R: 512 thr cover 64 rows x 8 chunks)
  const int srow = t >> 3, sc3 = t & 7;
  const int sxk = (sc3 ^ (srow & 7)) * 8;

  const int ntile = xe * 2 + 18;                // always even

  // ---- peeled prologue: stage tile 0 directly, prefetch tile 1 ----
  {
    half8 k0 = *(const half8*)&qkv[((size_t)srow * BATCH + b) * 3072 + 1024 + n * 64 + sc3 * 8];
    half8 v0 = *(const half8*)&vT[((size_t)bn * 64 + srow) * 2048 + sc3 * 8];
    *(half8*)&ldsK[srow][sxk] = k0;
    *(half8*)&ldsV[0][srow][sxk] = v0;
#pragma unroll
    for (int i = 0; i < 4; ++i) {
      const int ci = t + 512 * i;
      const int rr = ci >> 3, rc = ci & 7;
      const int pg = p0 + rr;
      const int ps = pg > 2047 ? 2047 : pg;
      const half8 rv = *(const half8*)&rbuf[(size_t)ps * 1024 + n * 64 + rc * 8];
      *(half8*)&ldsR[pg & 255][(rc ^ (pg & 7)) * 8] = rv;
    }
  }
  half8 kreg, vreg, rpre;  // steady-state prefetch regs
  ATT_PREFETCH(1);
  __syncthreads();
  ATT_QKMFMA(0);
  ATT_FOLD();

  // ---- main pipelined loop ----
  for (int kt = 1; kt < ntile; ++kt) {
    const int par = kt & 1;
    ATT_STAGE(kt, par);
    ATT_PREFETCH(kt + 1);
    ATT_QKMFMA(kt);          // MFMAs in flight -> ac, ea
    ATT_SOFTMAX(kt - 1);     // exp2/VALU of prev tile overlaps MFMA drain
    ATT_FOLD();              // first consumer of ea; -> S (tile kt)
    ATT_PV(par ^ 1);         // PV of prev tile (ldsV other buffer)
  }
  ATT_SOFTMAX(ntile - 1);    // drain
  ATT_PV((ntile - 1) & 1);

  // final l-sum reduction + normalize + store
#pragma unroll
  for (int r = 0; r < 4; ++r) {
    float l = lpart[r];
#pragma unroll
    for (int off = 1; off < 16; off <<= 1) l += __shfl_xor(l, off);
    const float inv = 1.0f / l;
    const int ig = i_base + quad * 4 + r;
#pragma unroll
    for (int dnt = 0; dnt < 4; ++dnt)
      av[((size_t)ig * BATCH + b) * 1024 + n * 64 + dnt * 16 + l15] = (half_t)(oacc[dnt][r] * inv);
  }
}

// -------- residual + LayerNorm (one block per row; sums 2 fp16 partials) ----
__global__ __launch_bounds__(256) void k_ln(const float* __restrict__ x,
                                            const half_t* __restrict__ ao0,
                                            const half_t* __restrict__ ao1,
                                            const float* __restrict__ gamma,
                                            const float* __restrict__ beta,
                                            float* __restrict__ out) {
  const int row = blockIdx.x;
  const int t = threadIdx.x;
  const float4 xv = ((const float4*)(x + (size_t)row * 1024))[t];
  const half4v a4 = ((const half4v*)(ao0 + (size_t)row * 1024))[t];
  const half4v b4 = ((const half4v*)(ao1 + (size_t)row * 1024))[t];
  const float y0 = xv.x + (float)a4[0] + (float)b4[0];
  const float y1 = xv.y + (float)a4[1] + (float)b4[1];
  const float y2 = xv.z + (float)a4[2] + (float)b4[2];
  const float y3 = xv.w + (float)a4[3] + (float)b4[3];
  float s = y0 + y1 + y2 + y3;
  float ss = y0 * y0 + y1 * y1 + y2 * y2 + y3 * y3;
#pragma unroll
  for (int off = 1; off < 64; off <<= 1) {
    s += __shfl_xor(s, off);
    ss += __shfl_xor(ss, off);
  }
  __shared__ float sb[4], ssb[4];
  if ((t & 63) == 0) { sb[t >> 6] = s; ssb[t >> 6] = ss; }
  __syncthreads();
  s = sb[0] + sb[1] + sb[2] + sb[3];
  ss = ssb[0] + ssb[1] + ssb[2] + ssb[3];
  const float mean = s * (1.f / 1024.f);
  const float var = ss * (1.f / 1024.f) - mean * mean;
  const float rstd = rsqrtf(var + 1e-5f);
  const float4 g = ((const float4*)gamma)[t];
  const float4 be = ((const float4*)beta)[t];
  float4 o;
  o.x = (y0 - mean) * rstd * g.x + be.x;
  o.y = (y1 - mean) * rstd * g.y + be.y;
  o.z = (y2 - mean) * rstd * g.z + be.z;
  o.w = (y3 - mean) * rstd * g.w + be.w;
  ((float4*)(out + (size_t)row * 1024))[t] = o;
}

// ---------------------------------------------------------------------------
extern "C" void kernel_launch(void* const* d_in, const int* in_sizes, int n_in,
                              void* d_out, int out_size, void* d_ws, size_t ws_size,
                              hipStream_t stream) {
  const float* x     = (const float*)d_in[0];
  const float* pos   = (const float*)d_in[1];
  const float* pbu   = (const float*)d_in[2];
  const float* pbv   = (const float*)d_in[3];
  const float* mem   = (const float*)d_in[4];
  const float* Wqkv  = (const float*)d_in[5];
  const float* Wrel  = (const float*)d_in[6];
  const float* Wo    = (const float*)d_in[7];
  const float* gamma = (const float*)d_in[8];
  const float* beta  = (const float*)d_in[9];
  float* out = (float*)d_out;

  half_t* ws    = (half_t*)d_ws;
  half_t* cbf   = ws;                 // [8192][1024]
  half_t* posb  = cbf + 8388608;      // [2048][1024]
  half_t* wqkvT = posb + 2097152;     // [3072][1024]
  half_t* wrelT = wqkvT + 3145728;    // [1024][1024]
  half_t* woT   = wrelT + 1048576;    // [1024][1024]
  half_t* qkv   = woT + 1048576;      // [8192][3072]
  half_t* rb    = qkv + 25165824;     // [2048][1024]
  half_t* vT    = rb + 2097152;       // [64][64][2048]
  half_t* av    = vT + 8388608;       // [4096][1024]
  half_t* aout0 = qkv;                // reuse qkv region (partial 0)
  half_t* aout1 = qkv + 4194304;      // partial 1

  k_convert3<<<10240, 256, 0, stream>>>(mem, x, pos, cbf, posb);
  k_transpose_w3<<<dim3(16, 80), 256, 0, stream>>>(Wqkv, Wrel, Wo, wqkvT, wrelT, woT);
  k_gemm_qkv_pos<<<1664, 256, 0, stream>>>(cbf, wqkvT, qkv, posb, wrelT, rb);
  k_transpose_v<<<dim3(32, 64), 256, 0, stream>>>(qkv, vT);
  k_attn<<<dim3(8, 64), 512, 0, stream>>>(qkv, rb, vT, pbu, pbv, av);
  k_gemm_proj<<<512, 256, 0, stream>>>(av, woT, aout0, aout1);
  k_ln<<<4096, 256, 0, stream>>>(x, aout0, aout1, gamma, beta, out);
}

// Round 5
// 330.541 us; speedup vs baseline: 1.3832x; 1.1263x over previous
//
#include <hip/hip_runtime.h>
#include <math.h>
#include <cstdint>
#include <cstddef>

// ---------------------------------------------------------------------------
// Transformer-XL relative multihead attention, MI355X (gfx950)
// S=1024, M=1024, T=2048, B=4, D=1024, H=16, DH=64
// R13: k_attn reverted to R8 verbatim (93.5us proven; R9-R12 pipeline attempts
//      all spilled or regressed). New lever: qkv+pos GEMM rebuilt as 256^2
//      tile / 8-wave / double-buffered LDS / 2-phase pipeline (issue next
//      K-tile's global_load_lds BEFORE computing current; single
//      vmcnt(0)+barrier per K-tile). Same XOR-swizzle staging/read lane math
//      as the proven 128^2 gemm_body. 416 blocks, bijective XCD swizzle.
// ---------------------------------------------------------------------------

typedef _Float16 half_t;
typedef _Float16 half8 __attribute__((ext_vector_type(8)));
typedef _Float16 half4v __attribute__((ext_vector_type(4)));
typedef float f32x4 __attribute__((ext_vector_type(4)));

#define S_LEN 1024
#define M_LEN 1024
#define T_LEN 2048
#define BATCH 4
#define NHEAD 16

__device__ inline void async_copy16(const half_t* g, half_t* l) {
  __builtin_amdgcn_global_load_lds(
      (const __attribute__((address_space(1))) void*)g,
      (__attribute__((address_space(3))) void*)l, 16, 0, 0);
}

// ---------------- fused fp32 -> fp16 convert: mem | x | pos ----------------
__global__ __launch_bounds__(256) void k_convert3(const float* __restrict__ mem,
                                                  const float* __restrict__ x,
                                                  const float* __restrict__ pos,
                                                  half_t* __restrict__ cbf,
                                                  half_t* __restrict__ posb) {
  const int i = blockIdx.x * 256 + threadIdx.x;  // grid covers 2621440 float4s
  const float* src;
  half_t* dst;
  int off;
  if (i < 1048576)      { src = mem; dst = cbf;           off = i; }
  else if (i < 2097152) { src = x;   dst = cbf + 4194304; off = i - 1048576; }
  else                  { src = pos; dst = posb;          off = i - 2097152; }
  const float4 v = ((const float4*)src)[off];
  half4v h;
  h[0] = (half_t)v.x; h[1] = (half_t)v.y; h[2] = (half_t)v.z; h[3] = (half_t)v.w;
  ((half4v*)dst)[off] = h;
}

// ------- fused transpose+convert of the 3 weights: [1024][C] -> [C][1024] ----
__global__ __launch_bounds__(256) void k_transpose_w3(const float* __restrict__ Wqkv,
                                                      const float* __restrict__ Wrel,
                                                      const float* __restrict__ Wo,
                                                      half_t* __restrict__ wqkvT,
                                                      half_t* __restrict__ wrelT,
                                                      half_t* __restrict__ woT) {
  __shared__ float tile[64][65];
  const int y = blockIdx.y;
  const float* src; half_t* dst; int C, c0;
  if (y < 48)      { src = Wqkv; dst = wqkvT; C = 3072; c0 = y * 64; }
  else if (y < 64) { src = Wrel; dst = wrelT; C = 1024; c0 = (y - 48) * 64; }
  else             { src = Wo;   dst = woT;   C = 1024; c0 = (y - 64) * 64; }
  const int t = threadIdx.x;
  const int r0 = blockIdx.x * 64;
  const int tx = t & 63, ty4 = t >> 6;
#pragma unroll
  for (int k = 0; k < 16; ++k) {
    int row = k * 4 + ty4;
    tile[row][tx] = src[(size_t)(r0 + row) * C + c0 + tx];
  }
  __syncthreads();
#pragma unroll
  for (int k = 0; k < 16; ++k) {
    int orow = k * 4 + ty4;
    dst[(size_t)(c0 + orow) * 1024 + r0 + tx] = (half_t)tile[tx][orow];
  }
}

// ---------------- fp16 GEMM core (m97 structure + XOR-swizzled LDS) --------
// kept for the (small) proj GEMM. ld = row stride of A and B.
__device__ inline void gemm_body(const half_t* __restrict__ A,
                                 const half_t* __restrict__ B,
                                 half_t* __restrict__ C,
                                 int N, int K, int ld, int m0, int n0,
                                 half_t (*ldsA)[64], half_t (*ldsB)[64]) {
  const int t = threadIdx.x;
  const int wave = t >> 6, lane = t & 63, quad = lane >> 4, l15 = lane & 15;
  const int wm = (wave >> 1) * 64, wn = (wave & 1) * 64;
  const int srow = lane >> 3;
  const int scol = ((lane & 7) ^ srow) * 8;  // XOR'd global source chunk
  f32x4 acc[4][4] = {};
  for (int k0 = 0; k0 < K; k0 += 64) {
    __syncthreads();
#pragma unroll
    for (int i = 0; i < 4; ++i) {
      const int r0 = (wave * 4 + i) * 8;
      async_copy16(&A[(size_t)(m0 + r0 + srow) * ld + k0 + scol], &ldsA[r0][0]);
      async_copy16(&B[(size_t)(n0 + r0 + srow) * ld + k0 + scol], &ldsB[r0][0]);
    }
    __syncthreads();
#pragma unroll
    for (int ks = 0; ks < 2; ++ks) {
      half8 af[4], bf[4];
#pragma unroll
      for (int mt = 0; mt < 4; ++mt)
        af[mt] = *(const half8*)&ldsA[wm + mt * 16 + l15][((ks * 4 + quad) ^ (l15 & 7)) * 8];
#pragma unroll
      for (int nt = 0; nt < 4; ++nt)
        bf[nt] = *(const half8*)&ldsB[wn + nt * 16 + l15][((ks * 4 + quad) ^ (l15 & 7)) * 8];
#pragma unroll
      for (int mt = 0; mt < 4; ++mt)
#pragma unroll
        for (int nt = 0; nt < 4; ++nt)
          acc[mt][nt] = __builtin_amdgcn_mfma_f32_16x16x32_f16(af[mt], bf[nt], acc[mt][nt], 0, 0, 0);
    }
  }
#pragma unroll
  for (int mt = 0; mt < 4; ++mt)
#pragma unroll
    for (int nt = 0; nt < 4; ++nt)
#pragma unroll
      for (int r = 0; r < 4; ++r) {
        const int row = m0 + wm + mt * 16 + quad * 4 + r;
        const int col = n0 + wn + nt * 16 + l15;
        C[(size_t)row * N + col] = (half_t)acc[mt][nt][r];
      }
}

// ------------- 256^2-tile double-buffered 2-phase GEMM: qkv + pos ----------
// 512 threads = 8 waves (2M x 4N); per-wave C = 128x64 (8x4 fragments).
// K-tiles of 64; stage(t+1) issued BEFORE compute(t); one vmcnt(0)+barrier
// per K-tile. Staging/read swizzle identical to gemm_body (proven).
#define QP_STAGE(buf_, k0_)                                                    \
  do {                                                                         \
    _Pragma("unroll") for (int i_ = 0; i_ < 4; ++i_) {                         \
      const int r0_ = wave * 32 + i_ * 8;                                      \
      async_copy16(&A[(size_t)(m0 + r0_ + srw) * 1024 + (k0_) + scl],          \
                   &ldsA[buf_][r0_][0]);                                       \
      async_copy16(&B[(size_t)(n0 + r0_ + srw) * 1024 + (k0_) + scl],          \
                   &ldsB[buf_][r0_][0]);                                       \
    }                                                                          \
  } while (0)

#define QP_COMPUTE(d_)                                                         \
  do {                                                                         \
    _Pragma("unroll") for (int ks_ = 0; ks_ < 2; ++ks_) {                      \
      half8 bf_[4];                                                            \
      _Pragma("unroll") for (int nt_ = 0; nt_ < 4; ++nt_) {                    \
        const int rw_ = wn + nt_ * 16 + l15;                                   \
        bf_[nt_] =                                                             \
            *(const half8*)&ldsB[d_][rw_][((ks_ * 4 + quad) ^ (rw_ & 7)) * 8]; \
      }                                                                        \
      half8 af_[8];                                                            \
      _Pragma("unroll") for (int mt_ = 0; mt_ < 8; ++mt_) {                    \
        const int rw_ = wm + mt_ * 16 + l15;                                   \
        af_[mt_] =                                                             \
            *(const half8*)&ldsA[d_][rw_][((ks_ * 4 + quad) ^ (rw_ & 7)) * 8]; \
      }                                                                        \
      __builtin_amdgcn_s_setprio(1);                                           \
      _Pragma("unroll") for (int mt_ = 0; mt_ < 8; ++mt_)                      \
        _Pragma("unroll") for (int nt_ = 0; nt_ < 4; ++nt_)                    \
          acc[mt_][nt_] = __builtin_amdgcn_mfma_f32_16x16x32_f16(              \
              af_[mt_], bf_[nt_], acc[mt_][nt_], 0, 0, 0);                     \
      __builtin_amdgcn_s_setprio(0);                                           \
    }                                                                          \
  } while (0)

__global__ __launch_bounds__(512, 2) void k_gemm_qkv_pos(const half_t* __restrict__ cbf,
                                                         const half_t* __restrict__ wqkvT,
                                                         half_t* __restrict__ qkv,
                                                         const half_t* __restrict__ posb,
                                                         const half_t* __restrict__ wrelT,
                                                         half_t* __restrict__ rb) {
  __shared__ half_t ldsA[2][256][64];   // 64 KB
  __shared__ half_t ldsB[2][256][64];   // 64 KB
  const int t = threadIdx.x;
  const int wave = t >> 6, lane = t & 63, quad = lane >> 4, l15 = lane & 15;
  // bijective XCD swizzle (416 % 8 == 0): each XCD gets a contiguous chunk
  const int bid0 = blockIdx.x;
  const int bid = (bid0 & 7) * 52 + (bid0 >> 3);
  const half_t* A; const half_t* B; half_t* C; int m0, n0, N;
  if (bid < 384) { A = cbf;  B = wqkvT; C = qkv; N = 3072;
                   m0 = (bid & 31) * 256; n0 = (bid >> 5) * 256; }
  else { const int b2 = bid - 384;
         A = posb; B = wrelT; C = rb;  N = 1024;
         m0 = (b2 & 7) * 256; n0 = (b2 >> 3) * 256; }
  // staging lane geometry (8 rows x 8 chunks per wave-call, XOR pre-swizzle)
  const int srw = lane >> 3;
  const int scl = ((lane & 7) ^ srw) * 8;
  const int wm = (wave >> 2) * 128, wn = (wave & 3) * 64;

  f32x4 acc[8][4] = {};

  QP_STAGE(0, 0);
  __syncthreads();            // drains vmcnt -> tile 0 staged for all waves
  int d = 0;
  for (int kt = 0; kt < 15; ++kt) {
    QP_STAGE(d ^ 1, (kt + 1) * 64);   // next tile's loads in flight...
    QP_COMPUTE(d);                    // ...while computing current
    __syncthreads();                  // drains vmcnt; next tile ready
    d ^= 1;
  }
  QP_COMPUTE(d);                      // last tile, no prefetch

#pragma unroll
  for (int mt = 0; mt < 8; ++mt)
#pragma unroll
    for (int nt = 0; nt < 4; ++nt)
#pragma unroll
      for (int r = 0; r < 4; ++r)
        C[(size_t)(m0 + wm + mt * 16 + quad * 4 + r) * N + n0 + wn + nt * 16 + l15] =
            (half_t)acc[mt][nt][r];
}

// proj GEMM, split-K=2: halves write fp16 partials summed in k_ln.
__global__ __launch_bounds__(256) void k_gemm_proj(const half_t* __restrict__ av,
                                                   const half_t* __restrict__ woT,
                                                   half_t* __restrict__ out0,
                                                   half_t* __restrict__ out1) {
  __shared__ half_t ldsA[128][64];
  __shared__ half_t ldsB[128][64];
  const int bid = blockIdx.x;
  const int h = bid >> 8, b2 = bid & 255;
  gemm_body(av + h * 512, woT + h * 512, h ? out1 : out0,
            1024, 512, 1024, (b2 & 31) * 128, (b2 >> 5) * 128, ldsA, ldsB);
}

// ---------------- V transpose: qkv v-slice -> vT[(b*16+n)*64+dh][T] ----------
__global__ __launch_bounds__(256) void k_transpose_v(const half_t* __restrict__ qkv,
                                                     half_t* __restrict__ vT) {
  __shared__ half_t tile[64][72];
  const int t = threadIdx.x;
  const int t0 = blockIdx.x * 64, bn = blockIdx.y, b = bn >> 4, n = bn & 15;
#pragma unroll
  for (int i = 0; i < 2; ++i) {
    const int ci = t + i * 256;
    const int row = ci >> 3, co = (ci & 7) * 8;
    *(half8*)&tile[row][co] =
        *(const half8*)&qkv[((size_t)(t0 + row) * BATCH + b) * 3072 + 2048 + n * 64 + co];
  }
  __syncthreads();
#pragma unroll
  for (int i = 0; i < 2; ++i) {
    const int ci = t + i * 256;
    const int dh = ci >> 3, to = (ci & 7) * 8;
    half8 v;
#pragma unroll
    for (int j = 0; j < 8; ++j) v[j] = tile[to + j][dh];
    *(half8*)&vT[((size_t)bn * 64 + dh) * 2048 + t0 + to] = v;
  }
}

// ---------------- flash attention with Transformer-XL relative shift --------
// R8 version, verbatim (93.5us proven). 512 threads = 8 waves; block owns 128
// queries. Pairing swizzle (x, 7-x). R ring buffer; single-buffer K/V
// prefetch; E shift via ds_bpermute in registers; P-only LDS; fixed-max
// softmax (C=4).
__global__ __launch_bounds__(512, 4) void k_attn(const half_t* __restrict__ qkv,
                                                 const half_t* __restrict__ rbuf,
                                                 const half_t* __restrict__ vT,
                                                 const float* __restrict__ pbu,
                                                 const float* __restrict__ pbv,
                                                 half_t* __restrict__ av) {
  __shared__ __align__(16) half_t ldsK[64][64];        // [key][dh], XOR chunks
  __shared__ __align__(16) half_t ldsV[64][64];        // [dh][key], XOR chunks
  __shared__ __align__(16) half_t ldsR[256][64];       // r ring, XOR chunks
  __shared__ __align__(16) half_t ldsP[8][16][72];     // per-wave P (wave-internal)
  const int t = threadIdx.x;
  const int wave = t >> 6, lane = t & 63, quad = lane >> 4, l15 = lane & 15;

  // work-pairing swizzle: CU-co-resident blocks get x and 7-x
  const int li = blockIdx.x + 8 * blockIdx.y;
  const int c = li & 255, kr = li >> 8;
  const int xe = kr == 0 ? (c & 7) : 7 - (c & 7);
  const int bn = (c >> 3) + (kr << 5);
  const int i0 = xe * 128;
  const int b = bn >> 4, n = bn & 15;
  const int i_base = i0 + wave * 16;
  const int p0 = 896 - i0;  // global r-row of ring origin at tile 0

  // q fragments with biases folded in
  half8 qu[2], qv[2];
#pragma unroll
  for (int ks = 0; ks < 2; ++ks) {
    const int dh0 = ks * 32 + quad * 8;
    const half8 qf = *(const half8*)&qkv[((size_t)(M_LEN + i_base + l15) * BATCH + b) * 3072 + n * 64 + dh0];
#pragma unroll
    for (int j = 0; j < 8; ++j) {
      const float qj = (float)qf[j];
      qu[ks][j] = (half_t)(qj + pbu[n * 64 + dh0 + j]);
      qv[ks][j] = (half_t)(qj + pbv[n * 64 + dh0 + j]);
    }
  }

  // E-shift lane rotation constants (loop-invariant): score col cj reads
  // window col cj + 15 - irow; rotation is uniform within a quad per r.
  int bperm_idx[4];
  bool lo_sel[4];
#pragma unroll
  for (int r = 0; r < 4; ++r) {
    const int irow = quad * 4 + r;
    bperm_idx[r] = ((lane & 48) | ((l15 + 15 - irow) & 15)) << 2;
    lo_sel[r] = (l15 <= irow);  // true: window col in tile nt; false: nt+1
  }

  f32x4 oacc[4] = {};
  float lpart[4] = {0.f, 0.f, 0.f, 0.f};
  const float k1 = 0.125f * 1.44269504088896f;  // scale * log2(e)
  const float kC = -4.0f * 1.44269504088896f;   // -C * log2(e)

  // staging geometry (K/V and steady-state R: 512 thr cover 64 rows x 8 chunks)
  const int srow = t >> 3, sc3 = t & 7;
  const int sxk = (sc3 ^ (srow & 7)) * 8;

  const int ntile = xe * 2 + 18;

  // ---- prologue: K/V tile 0, R ring rows [p0, p0+255] (4 passes) ----
  half8 kreg = *(const half8*)&qkv[((size_t)srow * BATCH + b) * 3072 + 1024 + n * 64 + sc3 * 8];
  half8 vreg = *(const half8*)&vT[((size_t)bn * 64 + srow) * 2048 + sc3 * 8];
  half8 rreg4[4];
  int rr4[4], rc4[4];
#pragma unroll
  for (int i = 0; i < 4; ++i) {
    const int ci = t + 512 * i;
    rr4[i] = ci >> 3; rc4[i] = ci & 7;
    const int ps = p0 + rr4[i] > 2047 ? 2047 : p0 + rr4[i];
    rreg4[i] = *(const half8*)&rbuf[(size_t)ps * 1024 + n * 64 + rc4[i] * 8];
  }
  half8 rpre;  // steady-state prefetch reg

  for (int kt = 0; kt < ntile; ++kt) {
    const int j0 = kt * 64;

    __syncthreads();  // prev-iter LDS reads done; drains vmcnt -> regs ready
    *(half8*)&ldsK[srow][sxk] = kreg;
    *(half8*)&ldsV[srow][sxk] = vreg;
    if (kt == 0) {
#pragma unroll
      for (int i = 0; i < 4; ++i) {
        const int pg = p0 + rr4[i];
        *(half8*)&ldsR[pg & 255][(rc4[i] ^ (pg & 7)) * 8] = rreg4[i];
      }
    } else {
      const int pw = j0 + p0 + 192 + srow;  // rows loaded during tile kt-1
      *(half8*)&ldsR[pw & 255][(sc3 ^ (pw & 7)) * 8] = rpre;
    }
    __syncthreads();

    // ---- prefetch tile kt+1 (regs dead after the writes above) ----
    if (kt + 1 < ntile) {
      const int j0n = j0 + 64;
      kreg = *(const half8*)&qkv[((size_t)(j0n + srow) * BATCH + b) * 3072 + 1024 + n * 64 + sc3 * 8];
      vreg = *(const half8*)&vT[((size_t)bn * 64 + srow) * 2048 + j0n + sc3 * 8];
      const int pn = j0 + p0 + 256 + srow;  // new ring rows for tile kt+1
      const int pc = pn > 2047 ? 2047 : pn;
      rpre = *(const half8*)&rbuf[(size_t)pc * 1024 + n * 64 + sc3 * 8];
    }

    // ---- AC = (q+u) @ K^T ----
    f32x4 ac[4] = {};
#pragma unroll
    for (int ks = 0; ks < 2; ++ks)
#pragma unroll
      for (int nt = 0; nt < 4; ++nt) {
        const int row = nt * 16 + l15;
        const half8 kf = *(const half8*)&ldsK[row][((ks * 4 + quad) ^ (row & 7)) * 8];
        ac[nt] = __builtin_amdgcn_mfma_f32_16x16x32_f16(qu[ks], kf, ac[nt], 0, 0, 0);
      }

    // ---- E window: E[m][c] = (q+v) . r[window c], width 80 (ring reads) ----
    const int rbg = j0 + p0 + 112 - wave * 16;  // wave's window start (global)
    f32x4 ea[5] = {};
#pragma unroll
    for (int ks = 0; ks < 2; ++ks)
#pragma unroll
      for (int et = 0; et < 5; ++et) {
        const int pr = rbg + et * 16 + l15;
        const half8 rf = *(const half8*)&ldsR[pr & 255][((ks * 4 + quad) ^ (pr & 7)) * 8];
        ea[et] = __builtin_amdgcn_mfma_f32_16x16x32_f16(qv[ks], rf, ea[et], 0, 0, 0);
      }

    // ---- scores -> p; E shift via in-register bpermute (f32) ----
    const bool maskt = j0 > i_base + 960;
#pragma unroll
    for (int r = 0; r < 4; ++r) {
      const int irow = quad * 4 + r;
      const int ig = i_base + irow;
      float rot[5];
#pragma unroll
      for (int et = 0; et < 5; ++et)
        rot[et] = __int_as_float(
            __builtin_amdgcn_ds_bpermute(bperm_idx[r], __float_as_int(ea[et][r])));
      float psum = 0.f;
#pragma unroll
      for (int nt = 0; nt < 4; ++nt) {
        const float ev = lo_sel[r] ? rot[nt] : rot[nt + 1];
        const int cj = nt * 16 + l15;
        float p = __builtin_amdgcn_exp2f(fmaf(ac[nt][r] + ev, k1, kC));
        if (maskt && (j0 + cj > ig + M_LEN)) p = 0.f;
        psum += p;
        ldsP[wave][irow][cj] = (half_t)p;
      }
      lpart[r] += psum;
    }
    __builtin_amdgcn_wave_barrier();  // P round trip is wave-internal

    // ---- PV ----
    half8 pa[2];
#pragma unroll
    for (int ks = 0; ks < 2; ++ks)
      pa[ks] = *(const half8*)&ldsP[wave][l15][ks * 32 + quad * 8];
#pragma unroll
    for (int ks = 0; ks < 2; ++ks)
#pragma unroll
      for (int dnt = 0; dnt < 4; ++dnt) {
        const int row = dnt * 16 + l15;
        const half8 vf = *(const half8*)&ldsV[row][((ks * 4 + quad) ^ (row & 7)) * 8];
        oacc[dnt] = __builtin_amdgcn_mfma_f32_16x16x32_f16(pa[ks], vf, oacc[dnt], 0, 0, 0);
      }
  }

  // final l-sum reduction + normalize + store
#pragma unroll
  for (int r = 0; r < 4; ++r) {
    float l = lpart[r];
#pragma unroll
    for (int off = 1; off < 16; off <<= 1) l += __shfl_xor(l, off);
    const float inv = 1.0f / l;
    const int ig = i_base + quad * 4 + r;
#pragma unroll
    for (int dnt = 0; dnt < 4; ++dnt)
      av[((size_t)ig * BATCH + b) * 1024 + n * 64 + dnt * 16 + l15] = (half_t)(oacc[dnt][r] * inv);
  }
}

// -------- residual + LayerNorm (one block per row; sums 2 fp16 partials) ----
__global__ __launch_bounds__(256) void k_ln(const float* __restrict__ x,
                                            const half_t* __restrict__ ao0,
                                            const half_t* __restrict__ ao1,
                                            const float* __restrict__ gamma,
                                            const float* __restrict__ beta,
                                            float* __restrict__ out) {
  const int row = blockIdx.x;
  const int t = threadIdx.x;
  const float4 xv = ((const float4*)(x + (size_t)row * 1024))[t];
  const half4v a4 = ((const half4v*)(ao0 + (size_t)row * 1024))[t];
  const half4v b4 = ((const half4v*)(ao1 + (size_t)row * 1024))[t];
  const float y0 = xv.x + (float)a4[0] + (float)b4[0];
  const float y1 = xv.y + (float)a4[1] + (float)b4[1];
  const float y2 = xv.z + (float)a4[2] + (float)b4[2];
  const float y3 = xv.w + (float)a4[3] + (float)b4[3];
  float s = y0 + y1 + y2 + y3;
  float ss = y0 * y0 + y1 * y1 + y2 * y2 + y3 * y3;
#pragma unroll
  for (int off = 1; off < 64; off <<= 1) {
    s += __shfl_xor(s, off);
    ss += __shfl_xor(ss, off);
  }
  __shared__ float sb[4], ssb[4];
  if ((t & 63) == 0) { sb[t >> 6] = s; ssb[t >> 6] = ss; }
  __syncthreads();
  s = sb[0] + sb[1] + sb[2] + sb[3];
  ss = ssb[0] + ssb[1] + ssb[2] + ssb[3];
  const float mean = s * (1.f / 1024.f);
  const float var = ss * (1.f / 1024.f) - mean * mean;
  const float rstd = rsqrtf(var + 1e-5f);
  const float4 g = ((const float4*)gamma)[t];
  const float4 be = ((const float4*)beta)[t];
  float4 o;
  o.x = (y0 - mean) * rstd * g.x + be.x;
  o.y = (y1 - mean) * rstd * g.y + be.y;
  o.z = (y2 - mean) * rstd * g.z + be.z;
  o.w = (y3 - mean) * rstd * g.w + be.w;
  ((float4*)(out + (size_t)row * 1024))[t] = o;
}

// ---------------------------------------------------------------------------
extern "C" void kernel_launch(void* const* d_in, const int* in_sizes, int n_in,
                              void* d_out, int out_size, void* d_ws, size_t ws_size,
                              hipStream_t stream) {
  const float* x     = (const float*)d_in[0];
  const float* pos   = (const float*)d_in[1];
  const float* pbu   = (const float*)d_in[2];
  const float* pbv   = (const float*)d_in[3];
  const float* mem   = (const float*)d_in[4];
  const float* Wqkv  = (const float*)d_in[5];
  const float* Wrel  = (const float*)d_in[6];
  const float* Wo    = (const float*)d_in[7];
  const float* gamma = (const float*)d_in[8];
  const float* beta  = (const float*)d_in[9];
  float* out = (float*)d_out;

  half_t* ws    = (half_t*)d_ws;
  half_t* cbf   = ws;                 // [8192][1024]
  half_t* posb  = cbf + 8388608;      // [2048][1024]
  half_t* wqkvT = posb + 2097152;     // [3072][1024]
  half_t* wrelT = wqkvT + 3145728;    // [1024][1024]
  half_t* woT   = wrelT + 1048576;    // [1024][1024]
  half_t* qkv   = woT + 1048576;      // [8192][3072]
  half_t* rb    = qkv + 25165824;     // [2048][1024]
  half_t* vT    = rb + 2097152;       // [64][64][2048]
  half_t* av    = vT + 8388608;       // [4096][1024]
  half_t* aout0 = qkv;                // reuse qkv region (partial 0)
  half_t* aout1 = qkv + 4194304;      // partial 1

  k_convert3<<<10240, 256, 0, stream>>>(mem, x, pos, cbf, posb);
  k_transpose_w3<<<dim3(16, 80), 256, 0, stream>>>(Wqkv, Wrel, Wo, wqkvT, wrelT, woT);
  k_gemm_qkv_pos<<<416, 512, 0, stream>>>(cbf, wqkvT, qkv, posb, wrelT, rb);
  k_transpose_v<<<dim3(32, 64), 256, 0, stream>>>(qkv, vT);
  k_attn<<<dim3(8, 64), 512, 0, stream>>>(qkv, rb, vT, pbu, pbv, av);
  k_gemm_proj<<<512, 256, 0, stream>>>(av, woT, aout0, aout1);
  k_ln<<<4096, 256, 0, stream>>>(x, aout0, aout1, gamma, beta, out);
}

// Round 6
// 308.394 us; speedup vs baseline: 1.4825x; 1.0718x over previous
//
#include <hip/hip_runtime.h>
#include <math.h>
#include <cstdint>
#include <cstddef>

// ---------------------------------------------------------------------------
// Transformer-XL relative multihead attention, MI355X (gfx950)
// S=1024, M=1024, T=2048, B=4, D=1024, H=16, DH=64
// R14: structural eliminations, no schedule changes.
//  (a) k_transpose_v deleted: vT computed directly as a transposed GEMM
//      (A = Wv^T rows, B = cbf rows -> C[vcol][b*2048+t]). Requires b-major
//      cbf/qkv ([B][T][D]); attn reads edited index-only (same arithmetic).
//  (b) k_convert3 + k_transpose_w3 merged into one k_pre launch.
//  k_attn is R8 verbatim except the 5 forced address edits (93.5us proven).
//  GEMM: R13's 256^2 / 8-wave / dbuf 2-phase, now QK(256) + vT(128) + pos(32)
//  = 416 blocks, bijective XCD swizzle.
// ---------------------------------------------------------------------------

typedef _Float16 half_t;
typedef _Float16 half8 __attribute__((ext_vector_type(8)));
typedef _Float16 half4v __attribute__((ext_vector_type(4)));
typedef float f32x4 __attribute__((ext_vector_type(4)));

#define S_LEN 1024
#define M_LEN 1024
#define T_LEN 2048
#define BATCH 4
#define NHEAD 16

__device__ inline void async_copy16(const half_t* g, half_t* l) {
  __builtin_amdgcn_global_load_lds(
      (const __attribute__((address_space(1))) void*)g,
      (__attribute__((address_space(3))) void*)l, 16, 0, 0);
}

// ---- fused pre-pass: convert (b-major cbf | posb) + weight transposes -----
// blocks [0,10240): fp32->fp16 convert of mem|x -> cbf[B][T][D], pos -> posb.
// blocks [10240,11520): 64x64 transpose+convert tiles of Wqkv|Wrel|Wo.
__global__ __launch_bounds__(256) void k_pre(const float* __restrict__ mem,
                                             const float* __restrict__ x,
                                             const float* __restrict__ pos,
                                             const float* __restrict__ Wqkv,
                                             const float* __restrict__ Wrel,
                                             const float* __restrict__ Wo,
                                             half_t* __restrict__ cbf,
                                             half_t* __restrict__ posb,
                                             half_t* __restrict__ wqkvT,
                                             half_t* __restrict__ wrelT,
                                             half_t* __restrict__ woT) {
  __shared__ float tile[64][65];
  const int bid = blockIdx.x;
  const int t = threadIdx.x;
  if (bid < 10240) {
    const int i = bid * 256 + t;  // 2621440 float4s total
    if (i < 2097152) {            // mem (sel=0) | x (sel=1), b-major dest
      const int off = i & 1048575;
      const int sel = i >> 20;
      const float4 v = ((const float4*)(sel ? x : mem))[off];
      const int row = off >> 8, d4 = off & 255;        // src row = t*4+b
      const int drow = (row & 3) * 2048 + sel * 1024 + (row >> 2);
      half4v h;
      h[0] = (half_t)v.x; h[1] = (half_t)v.y; h[2] = (half_t)v.z; h[3] = (half_t)v.w;
      ((half4v*)cbf)[(drow << 8) + d4] = h;
    } else {                      // pos, linear
      const int off = i - 2097152;
      const float4 v = ((const float4*)pos)[off];
      half4v h;
      h[0] = (half_t)v.x; h[1] = (half_t)v.y; h[2] = (half_t)v.z; h[3] = (half_t)v.w;
      ((half4v*)posb)[off] = h;
    }
    return;
  }
  // ---- weight transpose branch (barriers only here; whole blocks) ----
  const int tb = bid - 10240;
  const int bx = tb & 15, y = tb >> 4;
  const float* src; half_t* dst; int C, c0;
  if (y < 48)      { src = Wqkv; dst = wqkvT; C = 3072; c0 = y * 64; }
  else if (y < 64) { src = Wrel; dst = wrelT; C = 1024; c0 = (y - 48) * 64; }
  else             { src = Wo;   dst = woT;   C = 1024; c0 = (y - 64) * 64; }
  const int r0 = bx * 64;
  const int tx = t & 63, ty4 = t >> 6;
#pragma unroll
  for (int k = 0; k < 16; ++k) {
    int row = k * 4 + ty4;
    tile[row][tx] = src[(size_t)(r0 + row) * C + c0 + tx];
  }
  __syncthreads();
#pragma unroll
  for (int k = 0; k < 16; ++k) {
    int orow = k * 4 + ty4;
    dst[(size_t)(c0 + orow) * 1024 + r0 + tx] = (half_t)tile[tx][orow];
  }
}

// ---------------- fp16 GEMM core (m97 structure + XOR-swizzled LDS) --------
// kept for the (small) proj GEMM. ld = row stride of A and B.
__device__ inline void gemm_body(const half_t* __restrict__ A,
                                 const half_t* __restrict__ B,
                                 half_t* __restrict__ C,
                                 int N, int K, int ld, int m0, int n0,
                                 half_t (*ldsA)[64], half_t (*ldsB)[64]) {
  const int t = threadIdx.x;
  const int wave = t >> 6, lane = t & 63, quad = lane >> 4, l15 = lane & 15;
  const int wm = (wave >> 1) * 64, wn = (wave & 1) * 64;
  const int srow = lane >> 3;
  const int scol = ((lane & 7) ^ srow) * 8;  // XOR'd global source chunk
  f32x4 acc[4][4] = {};
  for (int k0 = 0; k0 < K; k0 += 64) {
    __syncthreads();
#pragma unroll
    for (int i = 0; i < 4; ++i) {
      const int r0 = (wave * 4 + i) * 8;
      async_copy16(&A[(size_t)(m0 + r0 + srow) * ld + k0 + scol], &ldsA[r0][0]);
      async_copy16(&B[(size_t)(n0 + r0 + srow) * ld + k0 + scol], &ldsB[r0][0]);
    }
    __syncthreads();
#pragma unroll
    for (int ks = 0; ks < 2; ++ks) {
      half8 af[4], bf[4];
#pragma unroll
      for (int mt = 0; mt < 4; ++mt)
        af[mt] = *(const half8*)&ldsA[wm + mt * 16 + l15][((ks * 4 + quad) ^ (l15 & 7)) * 8];
#pragma unroll
      for (int nt = 0; nt < 4; ++nt)
        bf[nt] = *(const half8*)&ldsB[wn + nt * 16 + l15][((ks * 4 + quad) ^ (l15 & 7)) * 8];
#pragma unroll
      for (int mt = 0; mt < 4; ++mt)
#pragma unroll
        for (int nt = 0; nt < 4; ++nt)
          acc[mt][nt] = __builtin_amdgcn_mfma_f32_16x16x32_f16(af[mt], bf[nt], acc[mt][nt], 0, 0, 0);
    }
  }
#pragma unroll
  for (int mt = 0; mt < 4; ++mt)
#pragma unroll
    for (int nt = 0; nt < 4; ++nt)
#pragma unroll
      for (int r = 0; r < 4; ++r) {
        const int row = m0 + wm + mt * 16 + quad * 4 + r;
        const int col = n0 + wn + nt * 16 + l15;
        C[(size_t)row * N + col] = (half_t)acc[mt][nt][r];
      }
}

// ------------- 256^2-tile double-buffered 2-phase GEMM: qk | vT | pos ------
// 512 threads = 8 waves (2M x 4N); per-wave C = 128x64 (8x4 fragments).
// K-tiles of 64; stage(t+1) issued BEFORE compute(t); one vmcnt(0)+barrier
// per K-tile. Staging/read swizzle identical to gemm_body (proven).
#define QP_STAGE(buf_, k0_)                                                    \
  do {                                                                         \
    _Pragma("unroll") for (int i_ = 0; i_ < 4; ++i_) {                         \
      const int r0_ = wave * 32 + i_ * 8;                                      \
      async_copy16(&A[(size_t)(m0 + r0_ + srw) * 1024 + (k0_) + scl],          \
                   &ldsA[buf_][r0_][0]);                                       \
      async_copy16(&B[(size_t)(n0 + r0_ + srw) * 1024 + (k0_) + scl],          \
                   &ldsB[buf_][r0_][0]);                                       \
    }                                                                          \
  } while (0)

#define QP_COMPUTE(d_)                                                         \
  do {                                                                         \
    _Pragma("unroll") for (int ks_ = 0; ks_ < 2; ++ks_) {                      \
      half8 bf_[4];                                                            \
      _Pragma("unroll") for (int nt_ = 0; nt_ < 4; ++nt_) {                    \
        const int rw_ = wn + nt_ * 16 + l15;                                   \
        bf_[nt_] =                                                             \
            *(const half8*)&ldsB[d_][rw_][((ks_ * 4 + quad) ^ (rw_ & 7)) * 8]; \
      }                                                                        \
      half8 af_[8];                                                            \
      _Pragma("unroll") for (int mt_ = 0; mt_ < 8; ++mt_) {                    \
        const int rw_ = wm + mt_ * 16 + l15;                                   \
        af_[mt_] =                                                             \
            *(const half8*)&ldsA[d_][rw_][((ks_ * 4 + quad) ^ (rw_ & 7)) * 8]; \
      }                                                                        \
      __builtin_amdgcn_s_setprio(1);                                           \
      _Pragma("unroll") for (int mt_ = 0; mt_ < 8; ++mt_)                      \
        _Pragma("unroll") for (int nt_ = 0; nt_ < 4; ++nt_)                    \
          acc[mt_][nt_] = __builtin_amdgcn_mfma_f32_16x16x32_f16(              \
              af_[mt_], bf_[nt_], acc[mt_][nt_], 0, 0, 0);                     \
      __builtin_amdgcn_s_setprio(0);                                           \
    }                                                                          \
  } while (0)

__global__ __launch_bounds__(512, 2) void k_gemm_qkv_pos(const half_t* __restrict__ cbf,
                                                         const half_t* __restrict__ wqkvT,
                                                         half_t* __restrict__ qkv,
                                                         const half_t* __restrict__ posb,
                                                         const half_t* __restrict__ wrelT,
                                                         half_t* __restrict__ rb,
                                                         half_t* __restrict__ vT) {
  __shared__ half_t ldsA[2][256][64];   // 64 KB
  __shared__ half_t ldsB[2][256][64];   // 64 KB
  const int t = threadIdx.x;
  const int wave = t >> 6, lane = t & 63, quad = lane >> 4, l15 = lane & 15;
  // bijective XCD swizzle (416 % 8 == 0): each XCD gets a contiguous chunk
  const int bid0 = blockIdx.x;
  const int bid = (bid0 & 7) * 52 + (bid0 >> 3);
  const half_t* A; const half_t* B; half_t* C; int m0, n0, N;
  if (bid < 256) {        // Q,K: cbf[8192] @ Wqk^T[2048] -> qkv[8192][2048]
    A = cbf;  B = wqkvT; C = qkv; N = 2048;
    m0 = (bid & 31) * 256; n0 = (bid >> 5) * 256;
  } else if (bid < 384) { // V^T: Wv^T[1024] @ cbf^T -> vT[1024][8192]
    const int b2 = bid - 256;
    A = wqkvT + 2048 * 1024; B = cbf; C = vT; N = 8192;
    m0 = (b2 & 3) * 256; n0 = (b2 >> 2) * 256;
  } else {                // pos: posb[2048] @ Wrel^T -> rb[2048][1024]
    const int b2 = bid - 384;
    A = posb; B = wrelT; C = rb; N = 1024;
    m0 = (b2 & 7) * 256; n0 = (b2 >> 3) * 256;
  }
  // staging lane geometry (8 rows x 8 chunks per wave-call, XOR pre-swizzle)
  const int srw = lane >> 3;
  const int scl = ((lane & 7) ^ srw) * 8;
  const int wm = (wave >> 2) * 128, wn = (wave & 3) * 64;

  f32x4 acc[8][4] = {};

  QP_STAGE(0, 0);
  __syncthreads();            // drains vmcnt -> tile 0 staged for all waves
  int d = 0;
  for (int kt = 0; kt < 15; ++kt) {
    QP_STAGE(d ^ 1, (kt + 1) * 64);   // next tile's loads in flight...
    QP_COMPUTE(d);                    // ...while computing current
    __syncthreads();                  // drains vmcnt; next tile ready
    d ^= 1;
  }
  QP_COMPUTE(d);                      // last tile, no prefetch

#pragma unroll
  for (int mt = 0; mt < 8; ++mt)
#pragma unroll
    for (int nt = 0; nt < 4; ++nt)
#pragma unroll
      for (int r = 0; r < 4; ++r)
        C[(size_t)(m0 + wm + mt * 16 + quad * 4 + r) * N + n0 + wn + nt * 16 + l15] =
            (half_t)acc[mt][nt][r];
}

// proj GEMM, split-K=2: halves write fp16 partials summed in k_ln.
__global__ __launch_bounds__(256) void k_gemm_proj(const half_t* __restrict__ av,
                                                   const half_t* __restrict__ woT,
                                                   half_t* __restrict__ out0,
                                                   half_t* __restrict__ out1) {
  __shared__ half_t ldsA[128][64];
  __shared__ half_t ldsB[128][64];
  const int bid = blockIdx.x;
  const int h = bid >> 8, b2 = bid & 255;
  gemm_body(av + h * 512, woT + h * 512, h ? out1 : out0,
            1024, 512, 1024, (b2 & 31) * 128, (b2 >> 5) * 128, ldsA, ldsB);
}

// ---------------- flash attention with Transformer-XL relative shift --------
// R8 version; only the 5 address lines forced by the b-major qkv[B][T][2048]
// and vT[1024][B*T] layouts differ (same arithmetic, same schedule).
__global__ __launch_bounds__(512, 4) void k_attn(const half_t* __restrict__ qkv,
                                                 const half_t* __restrict__ rbuf,
                                                 const half_t* __restrict__ vT,
                                                 const float* __restrict__ pbu,
                                                 const float* __restrict__ pbv,
                                                 half_t* __restrict__ av) {
  __shared__ __align__(16) half_t ldsK[64][64];        // [key][dh], XOR chunks
  __shared__ __align__(16) half_t ldsV[64][64];        // [dh][key], XOR chunks
  __shared__ __align__(16) half_t ldsR[256][64];       // r ring, XOR chunks
  __shared__ __align__(16) half_t ldsP[8][16][72];     // per-wave P (wave-internal)
  const int t = threadIdx.x;
  const int wave = t >> 6, lane = t & 63, quad = lane >> 4, l15 = lane & 15;

  // work-pairing swizzle: CU-co-resident blocks get x and 7-x
  const int li = blockIdx.x + 8 * blockIdx.y;
  const int c = li & 255, kr = li >> 8;
  const int xe = kr == 0 ? (c & 7) : 7 - (c & 7);
  const int bn = (c >> 3) + (kr << 5);
  const int i0 = xe * 128;
  const int b = bn >> 4, n = bn & 15;
  const int i_base = i0 + wave * 16;
  const int p0 = 896 - i0;  // global r-row of ring origin at tile 0

  // q fragments with biases folded in
  half8 qu[2], qv[2];
#pragma unroll
  for (int ks = 0; ks < 2; ++ks) {
    const int dh0 = ks * 32 + quad * 8;
    const half8 qf = *(const half8*)&qkv[((size_t)(b * 2048 + M_LEN + i_base + l15)) * 2048 + n * 64 + dh0];
#pragma unroll
    for (int j = 0; j < 8; ++j) {
      const float qj = (float)qf[j];
      qu[ks][j] = (half_t)(qj + pbu[n * 64 + dh0 + j]);
      qv[ks][j] = (half_t)(qj + pbv[n * 64 + dh0 + j]);
    }
  }

  // E-shift lane rotation constants (loop-invariant): score col cj reads
  // window col cj + 15 - irow; rotation is uniform within a quad per r.
  int bperm_idx[4];
  bool lo_sel[4];
#pragma unroll
  for (int r = 0; r < 4; ++r) {
    const int irow = quad * 4 + r;
    bperm_idx[r] = ((lane & 48) | ((l15 + 15 - irow) & 15)) << 2;
    lo_sel[r] = (l15 <= irow);  // true: window col in tile nt; false: nt+1
  }

  f32x4 oacc[4] = {};
  float lpart[4] = {0.f, 0.f, 0.f, 0.f};
  const float k1 = 0.125f * 1.44269504088896f;  // scale * log2(e)
  const float kC = -4.0f * 1.44269504088896f;   // -C * log2(e)

  // staging geometry (K/V and steady-state R: 512 thr cover 64 rows x 8 chunks)
  const int srow = t >> 3, sc3 = t & 7;
  const int sxk = (sc3 ^ (srow & 7)) * 8;

  const int ntile = xe * 2 + 18;

  // ---- prologue: K/V tile 0, R ring rows [p0, p0+255] (4 passes) ----
  half8 kreg = *(const half8*)&qkv[((size_t)(b * 2048 + srow)) * 2048 + 1024 + n * 64 + sc3 * 8];
  half8 vreg = *(const half8*)&vT[((size_t)(n * 64 + srow)) * 8192 + b * 2048 + sc3 * 8];
  half8 rreg4[4];
  int rr4[4], rc4[4];
#pragma unroll
  for (int i = 0; i < 4; ++i) {
    const int ci = t + 512 * i;
    rr4[i] = ci >> 3; rc4[i] = ci & 7;
    const int ps = p0 + rr4[i] > 2047 ? 2047 : p0 + rr4[i];
    rreg4[i] = *(const half8*)&rbuf[(size_t)ps * 1024 + n * 64 + rc4[i] * 8];
  }
  half8 rpre;  // steady-state prefetch reg

  for (int kt = 0; kt < ntile; ++kt) {
    const int j0 = kt * 64;

    __syncthreads();  // prev-iter LDS reads done; drains vmcnt -> regs ready
    *(half8*)&ldsK[srow][sxk] = kreg;
    *(half8*)&ldsV[srow][sxk] = vreg;
    if (kt == 0) {
#pragma unroll
      for (int i = 0; i < 4; ++i) {
        const int pg = p0 + rr4[i];
        *(half8*)&ldsR[pg & 255][(rc4[i] ^ (pg & 7)) * 8] = rreg4[i];
      }
    } else {
      const int pw = j0 + p0 + 192 + srow;  // rows loaded during tile kt-1
      *(half8*)&ldsR[pw & 255][(sc3 ^ (pw & 7)) * 8] = rpre;
    }
    __syncthreads();

    // ---- prefetch tile kt+1 (regs dead after the writes above) ----
    if (kt + 1 < ntile) {
      const int j0n = j0 + 64;
      kreg = *(const half8*)&qkv[((size_t)(b * 2048 + j0n + srow)) * 2048 + 1024 + n * 64 + sc3 * 8];
      vreg = *(const half8*)&vT[((size_t)(n * 64 + srow)) * 8192 + b * 2048 + j0n + sc3 * 8];
      const int pn = j0 + p0 + 256 + srow;  // new ring rows for tile kt+1
      const int pc = pn > 2047 ? 2047 : pn;
      rpre = *(const half8*)&rbuf[(size_t)pc * 1024 + n * 64 + sc3 * 8];
    }

    // ---- AC = (q+u) @ K^T ----
    f32x4 ac[4] = {};
#pragma unroll
    for (int ks = 0; ks < 2; ++ks)
#pragma unroll
      for (int nt = 0; nt < 4; ++nt) {
        const int row = nt * 16 + l15;
        const half8 kf = *(const half8*)&ldsK[row][((ks * 4 + quad) ^ (row & 7)) * 8];
        ac[nt] = __builtin_amdgcn_mfma_f32_16x16x32_f16(qu[ks], kf, ac[nt], 0, 0, 0);
      }

    // ---- E window: E[m][c] = (q+v) . r[window c], width 80 (ring reads) ----
    const int rbg = j0 + p0 + 112 - wave * 16;  // wave's window start (global)
    f32x4 ea[5] = {};
#pragma unroll
    for (int ks = 0; ks < 2; ++ks)
#pragma unroll
      for (int et = 0; et < 5; ++et) {
        const int pr = rbg + et * 16 + l15;
        const half8 rf = *(const half8*)&ldsR[pr & 255][((ks * 4 + quad) ^ (pr & 7)) * 8];
        ea[et] = __builtin_amdgcn_mfma_f32_16x16x32_f16(qv[ks], rf, ea[et], 0, 0, 0);
      }

    // ---- scores -> p; E shift via in-register bpermute (f32) ----
    const bool maskt = j0 > i_base + 960;
#pragma unroll
    for (int r = 0; r < 4; ++r) {
      const int irow = quad * 4 + r;
      const int ig = i_base + irow;
      float rot[5];
#pragma unroll
      for (int et = 0; et < 5; ++et)
        rot[et] = __int_as_float(
            __builtin_amdgcn_ds_bpermute(bperm_idx[r], __float_as_int(ea[et][r])));
      float psum = 0.f;
#pragma unroll
      for (int nt = 0; nt < 4; ++nt) {
        const float ev = lo_sel[r] ? rot[nt] : rot[nt + 1];
        const int cj = nt * 16 + l15;
        float p = __builtin_amdgcn_exp2f(fmaf(ac[nt][r] + ev, k1, kC));
        if (maskt && (j0 + cj > ig + M_LEN)) p = 0.f;
        psum += p;
        ldsP[wave][irow][cj] = (half_t)p;
      }
      lpart[r] += psum;
    }
    __builtin_amdgcn_wave_barrier();  // P round trip is wave-internal

    // ---- PV ----
    half8 pa[2];
#pragma unroll
    for (int ks = 0; ks < 2; ++ks)
      pa[ks] = *(const half8*)&ldsP[wave][l15][ks * 32 + quad * 8];
#pragma unroll
    for (int ks = 0; ks < 2; ++ks)
#pragma unroll
      for (int dnt = 0; dnt < 4; ++dnt) {
        const int row = dnt * 16 + l15;
        const half8 vf = *(const half8*)&ldsV[row][((ks * 4 + quad) ^ (row & 7)) * 8];
        oacc[dnt] = __builtin_amdgcn_mfma_f32_16x16x32_f16(pa[ks], vf, oacc[dnt], 0, 0, 0);
      }
  }

  // final l-sum reduction + normalize + store
#pragma unroll
  for (int r = 0; r < 4; ++r) {
    float l = lpart[r];
#pragma unroll
    for (int off = 1; off < 16; off <<= 1) l += __shfl_xor(l, off);
    const float inv = 1.0f / l;
    const int ig = i_base + quad * 4 + r;
#pragma unroll
    for (int dnt = 0; dnt < 4; ++dnt)
      av[((size_t)ig * BATCH + b) * 1024 + n * 64 + dnt * 16 + l15] = (half_t)(oacc[dnt][r] * inv);
  }
}

// -------- residual + LayerNorm (one block per row; sums 2 fp16 partials) ----
__global__ __launch_bounds__(256) void k_ln(const float* __restrict__ x,
                                            const half_t* __restrict__ ao0,
                                            const half_t* __restrict__ ao1,
                                            const float* __restrict__ gamma,
                                            const float* __restrict__ beta,
                                            float* __restrict__ out) {
  const int row = blockIdx.x;
  const int t = threadIdx.x;
  const float4 xv = ((const float4*)(x + (size_t)row * 1024))[t];
  const half4v a4 = ((const half4v*)(ao0 + (size_t)row * 1024))[t];
  const half4v b4 = ((const half4v*)(ao1 + (size_t)row * 1024))[t];
  const float y0 = xv.x + (float)a4[0] + (float)b4[0];
  const float y1 = xv.y + (float)a4[1] + (float)b4[1];
  const float y2 = xv.z + (float)a4[2] + (float)b4[2];
  const float y3 = xv.w + (float)a4[3] + (float)b4[3];
  float s = y0 + y1 + y2 + y3;
  float ss = y0 * y0 + y1 * y1 + y2 * y2 + y3 * y3;
#pragma unroll
  for (int off = 1; off < 64; off <<= 1) {
    s += __shfl_xor(s, off);
    ss += __shfl_xor(ss, off);
  }
  __shared__ float sb[4], ssb[4];
  if ((t & 63) == 0) { sb[t >> 6] = s; ssb[t >> 6] = ss; }
  __syncthreads();
  s = sb[0] + sb[1] + sb[2] + sb[3];
  ss = ssb[0] + ssb[1] + ssb[2] + ssb[3];
  const float mean = s * (1.f / 1024.f);
  const float var = ss * (1.f / 1024.f) - mean * mean;
  const float rstd = rsqrtf(var + 1e-5f);
  const float4 g = ((const float4*)gamma)[t];
  const float4 be = ((const float4*)beta)[t];
  float4 o;
  o.x = (y0 - mean) * rstd * g.x + be.x;
  o.y = (y1 - mean) * rstd * g.y + be.y;
  o.z = (y2 - mean) * rstd * g.z + be.z;
  o.w = (y3 - mean) * rstd * g.w + be.w;
  ((float4*)(out + (size_t)row * 1024))[t] = o;
}

// ---------------------------------------------------------------------------
extern "C" void kernel_launch(void* const* d_in, const int* in_sizes, int n_in,
                              void* d_out, int out_size, void* d_ws, size_t ws_size,
                              hipStream_t stream) {
  const float* x     = (const float*)d_in[0];
  const float* pos   = (const float*)d_in[1];
  const float* pbu   = (const float*)d_in[2];
  const float* pbv   = (const float*)d_in[3];
  const float* mem   = (const float*)d_in[4];
  const float* Wqkv  = (const float*)d_in[5];
  const float* Wrel  = (const float*)d_in[6];
  const float* Wo    = (const float*)d_in[7];
  const float* gamma = (const float*)d_in[8];
  const float* beta  = (const float*)d_in[9];
  float* out = (float*)d_out;

  half_t* ws    = (half_t*)d_ws;
  half_t* cbf   = ws;                 // [4][2048][1024] b-major
  half_t* posb  = cbf + 8388608;      // [2048][1024]
  half_t* wqkvT = posb + 2097152;     // [3072][1024]
  half_t* wrelT = wqkvT + 3145728;    // [1024][1024]
  half_t* woT   = wrelT + 1048576;    // [1024][1024]
  half_t* qkv   = woT + 1048576;      // [4][2048][2048] b-major (Q|K)
  half_t* rb    = qkv + 16777216;     // [2048][1024]
  half_t* vT    = rb + 2097152;       // [1024][4*2048]
  half_t* av    = vT + 8388608;       // [4096][1024]
  half_t* aout0 = qkv;                // reuse qkv region (partial 0)
  half_t* aout1 = qkv + 4194304;      // partial 1

  k_pre<<<11520, 256, 0, stream>>>(mem, x, pos, Wqkv, Wrel, Wo, cbf, posb, wqkvT, wrelT, woT);
  k_gemm_qkv_pos<<<416, 512, 0, stream>>>(cbf, wqkvT, qkv, posb, wrelT, rb, vT);
  k_attn<<<dim3(8, 64), 512, 0, stream>>>(qkv, rb, vT, pbu, pbv, av);
  k_gemm_proj<<<512, 256, 0, stream>>>(av, woT, aout0, aout1);
  k_ln<<<4096, 256, 0, stream>>>(x, aout0, aout1, gamma, beta, out);
}